// Round 4
// baseline (236.445 us; speedup 1.0000x reference)
//
#include <hip/hip_runtime.h>
#include <hip/hip_bf16.h>
#include <cstddef>

typedef __attribute__((ext_vector_type(8))) short short8;
typedef __attribute__((ext_vector_type(4))) short short4v;
typedef __attribute__((ext_vector_type(4))) float floatx4;
typedef __hip_bfloat16 bf16;

#define NB 8
#define NC 256
#define ND 128
#define NN 3072
#define NKC 16            /* split-K chunks for G = x x^T */
#define BN_EPS 1e-5f

static __device__ __forceinline__ short f2s(float v) {
    bf16 h = __float2bfloat16(v);
    return *reinterpret_cast<short*>(&h);
}

// load 8 consecutive fp32, convert to bf16 short8 (MFMA operand)
static __device__ __forceinline__ short8 ld8cvt(const float* p) {
    floatx4 a = *(const floatx4*)p, b = *(const floatx4*)(p + 4);
    short8 r;
    r[0] = f2s(a[0]); r[1] = f2s(a[1]); r[2] = f2s(a[2]); r[3] = f2s(a[3]);
    r[4] = f2s(b[0]); r[5] = f2s(b[1]); r[6] = f2s(b[2]); r[7] = f2s(b[3]);
    return r;
}

// ---------------------------------------------------------------------------
// pre: blocks 0..255 -> sx[b][c] = sum_n x[b,c,n]  (also warms L3 with x)
//      blocks 256..263 -> thwT[c'][e] = bf16(theta_w[e][c'])  (transpose)
// ---------------------------------------------------------------------------
__global__ __launch_bounds__(256)
void pre_kernel(const float* __restrict__ x, const float* __restrict__ theta_w,
                float* __restrict__ sx, short* __restrict__ thwT)
{
    int blk = blockIdx.x;
    int t = threadIdx.x;
    if (blk < 256) {
        int b = blk >> 5;
        int c0 = (blk & 31) * 8;
        int r = t >> 5;            // 0..7
        int w32 = t & 31;
        const float* xr = x + ((size_t)b * NC + c0 + r) * NN;
        float s = 0.f;
#pragma unroll
        for (int k = 0; k < 24; ++k) {
            floatx4 v = *(const floatx4*)(xr + (size_t)(w32 + k * 32) * 4);
            s += v[0] + v[1] + v[2] + v[3];
        }
#pragma unroll
        for (int off = 16; off; off >>= 1) s += __shfl_down(s, off, 32);
        if (w32 == 0) sx[b * NC + c0 + r] = s;
    } else {
        int c0 = (blk - 256) * 32;
        int cl = t >> 3;           // 0..31
        int e0 = (t & 7) * 16;
#pragma unroll
        for (int j = 0; j < 16; ++j)
            thwT[(size_t)(c0 + cl) * ND + e0 + j] =
                f2s(theta_w[(size_t)(e0 + j) * NC + c0 + cl]);
    }
}

// ---------------------------------------------------------------------------
// gpart: G-partials, G = x x^T per batch (k = n, x is n-contiguous -> NO
// transpose, NO LDS, operands read direct-global fp32 + inline cvt).
// grid 512 = (b 8, kc 16, tile 4); 256 thr = 4 waves (2x2 of 64x64).
// ---------------------------------------------------------------------------
__global__ __launch_bounds__(256)
void gpart_kernel(const float* __restrict__ x, float* __restrict__ Gpart)
{
    int blk = blockIdx.x;
    int tile = blk & 3;
    int kc = (blk >> 2) & 15;
    int b = blk >> 6;
    int tr = tile >> 1, tc = tile & 1;
    int t = threadIdx.x, lane = t & 63, wave = t >> 6;
    int wr = wave >> 1, wc = wave & 1;
    int lm = lane & 15, lh = lane >> 4, lk = lh * 8;
    const float* xb = x + (size_t)b * NC * NN;
    int n0 = kc * (NN / NKC);      // 192 per chunk

    floatx4 zero = {0.f, 0.f, 0.f, 0.f};
    floatx4 acc[4][4];
#pragma unroll
    for (int i = 0; i < 4; ++i)
#pragma unroll
        for (int j = 0; j < 4; ++j) acc[i][j] = zero;

#pragma unroll
    for (int kk = 0; kk < 192; kk += 32) {
        short8 af[4], bf[4];
#pragma unroll
        for (int i = 0; i < 4; ++i)
            af[i] = ld8cvt(xb + (size_t)(tr * 128 + wr * 64 + i * 16 + lm) * NN
                           + n0 + kk + lk);
#pragma unroll
        for (int j = 0; j < 4; ++j)
            bf[j] = ld8cvt(xb + (size_t)(tc * 128 + wc * 64 + j * 16 + lm) * NN
                           + n0 + kk + lk);
#pragma unroll
        for (int i = 0; i < 4; ++i)
#pragma unroll
            for (int j = 0; j < 4; ++j)
                acc[i][j] = __builtin_amdgcn_mfma_f32_16x16x32_bf16(
                    af[i], bf[j], acc[i][j], 0, 0, 0);
    }
    float* Gf = Gpart + (size_t)blk * 16384;
#pragma unroll
    for (int i = 0; i < 4; ++i)
#pragma unroll
        for (int j = 0; j < 4; ++j)
#pragma unroll
            for (int rr = 0; rr < 4; ++rr)
                Gf[(size_t)(wr * 64 + i * 16 + lh * 4 + rr) * 128
                   + wc * 64 + j * 16 + lm] = acc[i][j][rr];
}

// ---------------------------------------------------------------------------
// gred: G[b][c][c'] = sum_kc Gpart  (fp32, 2 MB total)
// ---------------------------------------------------------------------------
__global__ __launch_bounds__(256)
void gred_kernel(const float* __restrict__ Gpart, float* __restrict__ G)
{
    int idx = blockIdx.x * 256 + threadIdx.x;   // float4 id, 131072 total
    int b = idx >> 14;
    int fo = (idx & 16383) * 4;
    int c = fo >> 8;
    int cp = fo & 255;
    const float* src = Gpart + ((size_t)b * 64 + (size_t)((c >> 7) * 2 + (cp >> 7))) * 16384
                     + (size_t)(c & 127) * 128 + (cp & 127);
    floatx4 s = {0.f, 0.f, 0.f, 0.f};
#pragma unroll
    for (int k = 0; k < NKC; ++k)
        s += *(const floatx4*)(src + (size_t)k * 65536);
    *(floatx4*)(G + (size_t)b * 65536 + fo) = s;
}

// ---------------------------------------------------------------------------
// chain: per-batch block (grid 8, 256 thr = 4 waves). fp32 intermediates.
//   psx = phi_w sx ; gsx = g_w sx
//   T1 = phi_w G            (128x256, K=256; B rows via G symmetry)
//   S  = T1 g_w^T + psx g_b^T + phi_b gsx^T + N phi_b g_b^T   (128x128)
//   W2 = w_w S^T            (256x128, K=128)
//   Qf = inv/N * (W2 thwT^T) (256x256, K=128, bf16 out, A-ready for out_kernel)
//   C2 = inv*((W2 theta_b)/N + w_b - mean) + beta
// ---------------------------------------------------------------------------
__global__ __launch_bounds__(256)
void chain_kernel(const float* __restrict__ G,
                  const float* __restrict__ phi_w, const float* __restrict__ phi_b,
                  const float* __restrict__ g_w, const float* __restrict__ g_b,
                  const float* __restrict__ theta_b,
                  const float* __restrict__ w_w, const float* __restrict__ w_b,
                  const float* __restrict__ gamma, const float* __restrict__ beta,
                  const float* __restrict__ mean, const float* __restrict__ var,
                  const float* __restrict__ sx, const short* __restrict__ thwT,
                  float* __restrict__ T1g, float* __restrict__ Sg,
                  float* __restrict__ W2g, short* __restrict__ QfB,
                  float* __restrict__ C2g)
{
    __shared__ float sxl[256];
    __shared__ float psxs[128], gsxs[128];
    int b = blockIdx.x;
    int t = threadIdx.x, lane = t & 63, wave = t >> 6;
    int lm = lane & 15, lh = lane >> 4, lk = lh * 8;
    int wr = wave >> 1, wc = wave & 1;
    const float* Gb = G + (size_t)b * 65536;
    floatx4 zero = {0.f, 0.f, 0.f, 0.f};

    if (t < 64) *(floatx4*)&sxl[t * 4] = *(const floatx4*)(sx + b * NC + t * 4);
    __syncthreads();
    {   // psx / gsx (vectorized dot with LDS sx)
        const float* wrow = (t < 128) ? (phi_w + (size_t)t * NC)
                                      : (g_w + (size_t)(t - 128) * NC);
        float s = 0.f;
#pragma unroll
        for (int k = 0; k < 64; ++k) {
            floatx4 v = *(const floatx4*)(wrow + k * 4);
            s += v[0]*sxl[k*4] + v[1]*sxl[k*4+1] + v[2]*sxl[k*4+2] + v[3]*sxl[k*4+3];
        }
        if (t < 128) psxs[t] = s; else gsxs[t - 128] = s;
    }

    // ---- T1 = phi_w . G  (wave tile 64e x 128c')
    {
        floatx4 acc[4][8];
#pragma unroll
        for (int i = 0; i < 4; ++i)
#pragma unroll
            for (int j = 0; j < 8; ++j) acc[i][j] = zero;
#pragma unroll
        for (int kk = 0; kk < 256; kk += 32) {
            short8 af[4], bf[8];
#pragma unroll
            for (int i = 0; i < 4; ++i)
                af[i] = ld8cvt(phi_w + (size_t)(wr * 64 + i * 16 + lm) * NC + kk + lk);
#pragma unroll
            for (int j = 0; j < 8; ++j)
                bf[j] = ld8cvt(Gb + (size_t)(wc * 128 + j * 16 + lm) * NC + kk + lk);
#pragma unroll
            for (int i = 0; i < 4; ++i)
#pragma unroll
                for (int j = 0; j < 8; ++j)
                    acc[i][j] = __builtin_amdgcn_mfma_f32_16x16x32_bf16(
                        af[i], bf[j], acc[i][j], 0, 0, 0);
        }
        float* T1b = T1g + (size_t)b * 32768;
#pragma unroll
        for (int i = 0; i < 4; ++i)
#pragma unroll
            for (int j = 0; j < 8; ++j)
#pragma unroll
                for (int rr = 0; rr < 4; ++rr)
                    T1b[(size_t)(wr * 64 + i * 16 + lh * 4 + rr) * 256
                        + wc * 128 + j * 16 + lm] = acc[i][j][rr];
    }
    __syncthreads();

    // ---- S = T1 . g_w^T + biases  (wave tile 64e x 64d)
    {
        const float* T1b = T1g + (size_t)b * 32768;
        floatx4 acc[4][4];
#pragma unroll
        for (int i = 0; i < 4; ++i)
#pragma unroll
            for (int j = 0; j < 4; ++j) acc[i][j] = zero;
#pragma unroll
        for (int kk = 0; kk < 256; kk += 32) {
            short8 af[4], bf[4];
#pragma unroll
            for (int i = 0; i < 4; ++i)
                af[i] = ld8cvt(T1b + (size_t)(wr * 64 + i * 16 + lm) * 256 + kk + lk);
#pragma unroll
            for (int j = 0; j < 4; ++j)
                bf[j] = ld8cvt(g_w + (size_t)(wc * 64 + j * 16 + lm) * NC + kk + lk);
#pragma unroll
            for (int i = 0; i < 4; ++i)
#pragma unroll
                for (int j = 0; j < 4; ++j)
                    acc[i][j] = __builtin_amdgcn_mfma_f32_16x16x32_bf16(
                        af[i], bf[j], acc[i][j], 0, 0, 0);
        }
        float* Sb = Sg + (size_t)b * 16384;
#pragma unroll
        for (int i = 0; i < 4; ++i)
#pragma unroll
            for (int j = 0; j < 4; ++j)
#pragma unroll
                for (int rr = 0; rr < 4; ++rr) {
                    int e = wr * 64 + i * 16 + lh * 4 + rr;
                    int d = wc * 64 + j * 16 + lm;
                    float v = acc[i][j][rr] + psxs[e] * g_b[d]
                            + phi_b[e] * gsxs[d]
                            + (float)NN * phi_b[e] * g_b[d];
                    Sb[(size_t)e * 128 + d] = v;
                }
    }
    __syncthreads();

    // ---- W2 = w_w . S^T  (wave owns 64 c rows, full e=128)
    {
        const float* Sb = Sg + (size_t)b * 16384;
        floatx4 acc[4][8];
#pragma unroll
        for (int i = 0; i < 4; ++i)
#pragma unroll
            for (int j = 0; j < 8; ++j) acc[i][j] = zero;
#pragma unroll
        for (int kk = 0; kk < 128; kk += 32) {
            short8 af[4], bf[8];
#pragma unroll
            for (int i = 0; i < 4; ++i)
                af[i] = ld8cvt(w_w + (size_t)(wave * 64 + i * 16 + lm) * ND + kk + lk);
#pragma unroll
            for (int j = 0; j < 8; ++j)
                bf[j] = ld8cvt(Sb + (size_t)(j * 16 + lm) * 128 + kk + lk);
#pragma unroll
            for (int i = 0; i < 4; ++i)
#pragma unroll
                for (int j = 0; j < 8; ++j)
                    acc[i][j] = __builtin_amdgcn_mfma_f32_16x16x32_bf16(
                        af[i], bf[j], acc[i][j], 0, 0, 0);
        }
        float* W2b = W2g + (size_t)b * 32768;
#pragma unroll
        for (int i = 0; i < 4; ++i)
#pragma unroll
            for (int j = 0; j < 8; ++j)
#pragma unroll
                for (int rr = 0; rr < 4; ++rr)
                    W2b[(size_t)(wave * 64 + i * 16 + lh * 4 + rr) * 128
                        + j * 16 + lm] = acc[i][j][rr];
    }
    __syncthreads();

    // ---- Qf (2 passes over c' halves) + C2
    {
        const float* W2b = W2g + (size_t)b * 32768;
#pragma unroll
        for (int half = 0; half < 2; ++half) {
            floatx4 acc[4][8];
#pragma unroll
            for (int i = 0; i < 4; ++i)
#pragma unroll
                for (int j = 0; j < 8; ++j) acc[i][j] = zero;
#pragma unroll
            for (int kk = 0; kk < 128; kk += 32) {
                short8 af[4], bf[8];
#pragma unroll
                for (int i = 0; i < 4; ++i)
                    af[i] = ld8cvt(W2b + (size_t)(wave * 64 + i * 16 + lm) * 128 + kk + lk);
#pragma unroll
                for (int j = 0; j < 8; ++j)
                    bf[j] = *(const short8*)(thwT
                            + (size_t)(half * 128 + j * 16 + lm) * ND + kk + lk);
#pragma unroll
                for (int i = 0; i < 4; ++i)
#pragma unroll
                    for (int j = 0; j < 8; ++j)
                        acc[i][j] = __builtin_amdgcn_mfma_f32_16x16x32_bf16(
                            af[i], bf[j], acc[i][j], 0, 0, 0);
            }
#pragma unroll
            for (int i = 0; i < 4; ++i)
#pragma unroll
                for (int rr = 0; rr < 4; ++rr) {
                    int c = wave * 64 + i * 16 + lh * 4 + rr;
                    float iv = gamma[c] * rsqrtf(var[c] + BN_EPS) * (1.f / (float)NN);
#pragma unroll
                    for (int j = 0; j < 8; ++j)
                        QfB[(size_t)b * 65536 + (size_t)c * 256
                            + half * 128 + j * 16 + lm] = f2s(acc[i][j][rr] * iv);
                }
        }
        // C2
        {
            int c = t;
            const float* wrow = W2b + (size_t)c * 128;
            float s = 0.f;
#pragma unroll
            for (int e = 0; e < 128; ++e) s += wrow[e] * theta_b[e];
            float iv = gamma[c] * rsqrtf(var[c] + BN_EPS);
            C2g[b * NC + c] = iv * (s * (1.f / (float)NN) + w_b[c] - mean[c]) + beta[c];
        }
    }
}

// ---------------------------------------------------------------------------
// out: out[c,n] = sum_c' Qf[c,c'] x[c',n] + C2[c] + x[c,n]
// grid (32 n-tiles x 8 b) = 256 blocks, 512 thr = 8 waves (4c x 2n),
// wave tile 64c x 48n. A direct from QfB (L2-hot); x via LDS transpose with
// T14 reg-prefetch (A-frags issued BEFORE prefetch so MFMA wait leaves the
// prefetch in flight).
// ---------------------------------------------------------------------------
__global__ __launch_bounds__(512, 2)
void out_kernel(const short* __restrict__ QfB, const float* __restrict__ C2g,
                const float* __restrict__ x, float* __restrict__ out)
{
    __shared__ short Xs[96][72];
    int blk = blockIdx.x;
    int b = blk >> 5;
    int n0 = (blk & 31) * 96;
    int t = threadIdx.x, lane = t & 63, wave = t >> 6;
    int lm = lane & 15, lh = lane >> 4, lk = lh * 8;
    int wr = wave >> 1, wc = wave & 1;
    const float* xb = x + (size_t)b * NC * NN;
    const short* Qb = QfB + (size_t)b * 65536;

    floatx4 zero = {0.f, 0.f, 0.f, 0.f};
    floatx4 acc[4][3];
#pragma unroll
    for (int i = 0; i < 4; ++i)
#pragma unroll
        for (int j = 0; j < 3; ++j) acc[i][j] = zero;

    int sn = t % 96, cgp = t / 96;   // valid for t < 384
    float xf[16];
    if (t < 384) {
#pragma unroll
        for (int j = 0; j < 16; ++j)
            xf[j] = xb[(size_t)(cgp * 16 + j) * NN + n0 + sn];
    }

#pragma unroll
    for (int kt = 0; kt < NC; kt += 64) {
        __syncthreads();
        // A-frags for whole kt (oldest in vmcnt queue)
        short8 af2[2][4];
#pragma unroll
        for (int h = 0; h < 2; ++h)
#pragma unroll
            for (int i = 0; i < 4; ++i)
                af2[h][i] = *(const short8*)(Qb
                        + (size_t)(wr * 64 + i * 16 + lm) * 256 + kt + h * 32 + lk);
        // write-late: x chunk -> Xs
        if (t < 384) {
            short8 s0, s1;
#pragma unroll
            for (int j = 0; j < 8; ++j) {
                s0[j] = f2s(xf[j]);
                s1[j] = f2s(xf[8 + j]);
            }
            *(short8*)&Xs[sn][cgp * 16]     = s0;
            *(short8*)&Xs[sn][cgp * 16 + 8] = s1;
        }
        __syncthreads();
        // issue-early: next kt's x (newest; stays in flight under MFMA)
        if (t < 384 && kt < NC - 64) {
#pragma unroll
            for (int j = 0; j < 16; ++j)
                xf[j] = xb[(size_t)(kt + 64 + cgp * 16 + j) * NN + n0 + sn];
        }
#pragma unroll
        for (int h = 0; h < 2; ++h) {
            short8 bfr[3];
#pragma unroll
            for (int j = 0; j < 3; ++j)
                bfr[j] = *(const short8*)&Xs[wc * 48 + j * 16 + lm][h * 32 + lk];
#pragma unroll
            for (int i = 0; i < 4; ++i)
#pragma unroll
                for (int j = 0; j < 3; ++j)
                    acc[i][j] = __builtin_amdgcn_mfma_f32_16x16x32_bf16(
                        af2[h][i], bfr[j], acc[i][j], 0, 0, 0);
        }
    }

    float* Cf = out + (size_t)b * NC * NN;
#pragma unroll
    for (int i = 0; i < 4; ++i) {
#pragma unroll
        for (int rr = 0; rr < 4; ++rr) {
            int c = wr * 64 + i * 16 + lh * 4 + rr;
            float c2 = C2g[b * NC + c];
#pragma unroll
            for (int j = 0; j < 3; ++j) {
                size_t idx = (size_t)c * NN + n0 + wc * 48 + j * 16 + lm;
                Cf[idx] = acc[i][j][rr] + c2 + xb[idx];
            }
        }
    }
}

extern "C" void kernel_launch(void* const* d_in, const int* in_sizes, int n_in,
                              void* d_out, int out_size, void* d_ws, size_t ws_size,
                              hipStream_t stream)
{
    const float* x       = (const float*)d_in[0];
    const float* g_w     = (const float*)d_in[1];
    const float* g_b     = (const float*)d_in[2];
    const float* theta_w = (const float*)d_in[3];
    const float* theta_b = (const float*)d_in[4];
    const float* phi_w   = (const float*)d_in[5];
    const float* phi_b   = (const float*)d_in[6];
    const float* w_w     = (const float*)d_in[7];
    const float* w_b     = (const float*)d_in[8];
    const float* gamma   = (const float*)d_in[9];
    const float* beta    = (const float*)d_in[10];
    const float* mean    = (const float*)d_in[11];
    const float* var     = (const float*)d_in[12];
    (void)in_sizes; (void)n_in; (void)out_size; (void)ws_size;

    char* w = (char*)d_ws;
    float* sx    = (float*)w; w += (size_t)NB * NC * 4;                 // 8 KB
    float* C2g   = (float*)w; w += (size_t)NB * NC * 4;                 // 8 KB
    short* thwT  = (short*)w; w += (size_t)NC * ND * 2;                 // 64 KB
    float* Gpart = (float*)w; w += (size_t)NB * NKC * 4 * 16384 * 4;    // 32 MB
    float* G     = (float*)w; w += (size_t)NB * NC * NC * 4;            // 2 MB
    float* T1g   = (float*)w; w += (size_t)NB * ND * NC * 4;            // 1 MB
    float* Sg    = (float*)w; w += (size_t)NB * ND * ND * 4;            // 512 KB
    float* W2g   = (float*)w; w += (size_t)NB * NC * ND * 4;            // 1 MB
    short* QfB   = (short*)w; w += (size_t)NB * NC * NC * 2;            // 1 MB

    pre_kernel<<<dim3(264), dim3(256), 0, stream>>>(x, theta_w, sx, thwT);

    gpart_kernel<<<dim3(NB * NKC * 4), dim3(256), 0, stream>>>(x, Gpart);

    gred_kernel<<<dim3(512), dim3(256), 0, stream>>>(Gpart, G);

    chain_kernel<<<dim3(NB), dim3(256), 0, stream>>>(
        G, phi_w, phi_b, g_w, g_b, theta_b, w_w, w_b,
        gamma, beta, mean, var, sx, thwT, T1g, Sg, W2g, QfB, C2g);

    out_kernel<<<dim3(256), dim3(512), 0, stream>>>(QfB, C2g, x, (float*)d_out);
}

// Round 5
// 224.691 us; speedup vs baseline: 1.0523x; 1.0523x over previous
//
#include <hip/hip_runtime.h>
#include <hip/hip_bf16.h>
#include <cstddef>

typedef __attribute__((ext_vector_type(8))) short short8;
typedef __attribute__((ext_vector_type(4))) short short4v;
typedef __attribute__((ext_vector_type(4))) float floatx4;
typedef __hip_bfloat16 bf16;

#define NB 8
#define NC 256
#define ND 128
#define NN 3072
#define NKC 8             /* split-K chunks for G = x x^T */
#define BN_EPS 1e-5f

static __device__ __forceinline__ short f2s(float v) {
    bf16 h = __float2bfloat16(v);
    return *reinterpret_cast<short*>(&h);
}

// load 8 consecutive fp32, convert to bf16 short8 (MFMA operand)
static __device__ __forceinline__ short8 ld8cvt(const float* p) {
    floatx4 a = *(const floatx4*)p, b = *(const floatx4*)(p + 4);
    short8 r;
    r[0] = f2s(a[0]); r[1] = f2s(a[1]); r[2] = f2s(a[2]); r[3] = f2s(a[3]);
    r[4] = f2s(b[0]); r[5] = f2s(b[1]); r[6] = f2s(b[2]); r[7] = f2s(b[3]);
    return r;
}

// ---------------------------------------------------------------------------
// prep: blk 0..255   -> sx[b][c] = sum_n x[b,c,n]
//       blk 256..259 -> U = w_w . g_w          (256x256, fp32), tile 128^2
//       blk 260..263 -> VT[c'][cm] = sum_e theta_w[e,c'] phi_w[e,cm]
//       blk 264      -> q = phi_w^T theta_b ; u1 = w_w g_b ; vb = theta_w^T phi_b
// U, VT, q, u1, vb are batch-independent.
// ---------------------------------------------------------------------------
__global__ __launch_bounds__(256)
void prep_kernel(const float* __restrict__ x,
                 const float* __restrict__ g_w, const float* __restrict__ g_b,
                 const float* __restrict__ theta_w, const float* __restrict__ theta_b,
                 const float* __restrict__ phi_w, const float* __restrict__ phi_b,
                 const float* __restrict__ w_w,
                 float* __restrict__ sx, float* __restrict__ U,
                 float* __restrict__ VT, float* __restrict__ qv,
                 float* __restrict__ u1v, float* __restrict__ vbv)
{
    __shared__ short TA[128][136];
    __shared__ short TB[128][136];
    int blk = blockIdx.x;
    int t = threadIdx.x;

    if (blk < 256) {          // sx
        int b = blk >> 5;
        int c0 = (blk & 31) * 8;
        int r = t >> 5;
        int w32 = t & 31;
        const float* xr = x + ((size_t)b * NC + c0 + r) * NN;
        float s = 0.f;
#pragma unroll
        for (int k = 0; k < 24; ++k) {
            floatx4 v = *(const floatx4*)(xr + (size_t)(w32 + k * 32) * 4);
            s += v[0] + v[1] + v[2] + v[3];
        }
#pragma unroll
        for (int off = 16; off; off >>= 1) s += __shfl_down(s, off, 32);
        if (w32 == 0) sx[b * NC + c0 + r] = s;
        return;
    }
    if (blk == 264) {         // small vectors
        int c = t;
        float s_q = 0.f, s_vb = 0.f, s_u1 = 0.f;
#pragma unroll
        for (int e = 0; e < 128; ++e) {
            s_q  += phi_w[(size_t)e * NC + c] * theta_b[e];
            s_vb += theta_w[(size_t)e * NC + c] * phi_b[e];
        }
        const float* wr_ = w_w + (size_t)c * ND;
#pragma unroll
        for (int d = 0; d < 32; ++d) {
            floatx4 v = *(const floatx4*)(wr_ + d * 4);
            floatx4 gb = *(const floatx4*)(g_b + d * 4);
            s_u1 += v[0]*gb[0] + v[1]*gb[1] + v[2]*gb[2] + v[3]*gb[3];
        }
        qv[c] = s_q; vbv[c] = s_vb; u1v[c] = s_u1;
        return;
    }

    int lane = t & 63, wave = t >> 6;
    int lm = lane & 15, lh = lane >> 4, lk = lh * 8;
    int wr = wave >> 1, wc = wave & 1;
    floatx4 zero = {0.f, 0.f, 0.f, 0.f};
    floatx4 acc[4][4];
#pragma unroll
    for (int i = 0; i < 4; ++i)
#pragma unroll
        for (int j = 0; j < 4; ++j) acc[i][j] = zero;

    if (blk < 260) {          // U tile
        int ti = blk - 256, tr = ti >> 1, tc = ti & 1;
        // TB[cm][d] = g_w[d][tc*128+cm]  (transpose-stage, bf16)
#pragma unroll
        for (int p = 0; p < 8; ++p) {
            int idx = p * 256 + t;
            int d = idx >> 4;
            int cg = (idx & 15) * 8;
            floatx4 v0 = *(const floatx4*)(g_w + (size_t)d * NC + tc * 128 + cg);
            floatx4 v1 = *(const floatx4*)(g_w + (size_t)d * NC + tc * 128 + cg + 4);
#pragma unroll
            for (int j = 0; j < 4; ++j) {
                TB[cg + j][d] = f2s(v0[j]);
                TB[cg + 4 + j][d] = f2s(v1[j]);
            }
        }
        __syncthreads();
#pragma unroll
        for (int kk = 0; kk < 128; kk += 32) {
            short8 af[4], bf[4];
#pragma unroll
            for (int i = 0; i < 4; ++i)
                af[i] = ld8cvt(w_w + (size_t)(tr * 128 + wr * 64 + i * 16 + lm) * ND + kk + lk);
#pragma unroll
            for (int j = 0; j < 4; ++j)
                bf[j] = *(const short8*)&TB[wc * 64 + j * 16 + lm][kk + lk];
#pragma unroll
            for (int i = 0; i < 4; ++i)
#pragma unroll
                for (int j = 0; j < 4; ++j)
                    acc[i][j] = __builtin_amdgcn_mfma_f32_16x16x32_bf16(
                        af[i], bf[j], acc[i][j], 0, 0, 0);
        }
#pragma unroll
        for (int i = 0; i < 4; ++i)
#pragma unroll
            for (int j = 0; j < 4; ++j)
#pragma unroll
                for (int rr = 0; rr < 4; ++rr)
                    U[(size_t)(tr * 128 + wr * 64 + i * 16 + lh * 4 + rr) * NC
                      + tc * 128 + wc * 64 + j * 16 + lm] = acc[i][j][rr];
    } else {                  // VT tile
        int ti = blk - 260, tr = ti >> 1, tc = ti & 1;
        // TA[c'l][e] = theta_w[e][tr*128+c'l]; TB[cm][e] = phi_w[e][tc*128+cm]
#pragma unroll
        for (int p = 0; p < 8; ++p) {
            int idx = p * 256 + t;
            int e = idx >> 4;
            int cg = (idx & 15) * 8;
            floatx4 a0 = *(const floatx4*)(theta_w + (size_t)e * NC + tr * 128 + cg);
            floatx4 a1 = *(const floatx4*)(theta_w + (size_t)e * NC + tr * 128 + cg + 4);
            floatx4 b0 = *(const floatx4*)(phi_w + (size_t)e * NC + tc * 128 + cg);
            floatx4 b1 = *(const floatx4*)(phi_w + (size_t)e * NC + tc * 128 + cg + 4);
#pragma unroll
            for (int j = 0; j < 4; ++j) {
                TA[cg + j][e] = f2s(a0[j]); TA[cg + 4 + j][e] = f2s(a1[j]);
                TB[cg + j][e] = f2s(b0[j]); TB[cg + 4 + j][e] = f2s(b1[j]);
            }
        }
        __syncthreads();
#pragma unroll
        for (int kk = 0; kk < 128; kk += 32) {
            short8 af[4], bf[4];
#pragma unroll
            for (int i = 0; i < 4; ++i)
                af[i] = *(const short8*)&TA[wr * 64 + i * 16 + lm][kk + lk];
#pragma unroll
            for (int j = 0; j < 4; ++j)
                bf[j] = *(const short8*)&TB[wc * 64 + j * 16 + lm][kk + lk];
#pragma unroll
            for (int i = 0; i < 4; ++i)
#pragma unroll
                for (int j = 0; j < 4; ++j)
                    acc[i][j] = __builtin_amdgcn_mfma_f32_16x16x32_bf16(
                        af[i], bf[j], acc[i][j], 0, 0, 0);
        }
#pragma unroll
        for (int i = 0; i < 4; ++i)
#pragma unroll
            for (int j = 0; j < 4; ++j)
#pragma unroll
                for (int rr = 0; rr < 4; ++rr)
                    VT[(size_t)(tr * 128 + wr * 64 + i * 16 + lh * 4 + rr) * NC
                       + tc * 128 + wc * 64 + j * 16 + lm] = acc[i][j][rr];
    }
}

// ---------------------------------------------------------------------------
// gpart: G-partials, G = x x^T per batch (k = n contiguous -> no transpose,
// no LDS, direct-global fp32 + inline cvt). grid 256 = (b 8, kc 8, tile 4).
// ---------------------------------------------------------------------------
__global__ __launch_bounds__(256)
void gpart_kernel(const float* __restrict__ x, float* __restrict__ Gpart)
{
    int blk = blockIdx.x;
    int tile = blk & 3;
    int kc = (blk >> 2) & 7;
    int b = blk >> 5;
    int tr = tile >> 1, tc = tile & 1;
    int t = threadIdx.x, lane = t & 63, wave = t >> 6;
    int wr = wave >> 1, wc = wave & 1;
    int lm = lane & 15, lh = lane >> 4, lk = lh * 8;
    const float* xb = x + (size_t)b * NC * NN;
    int n0 = kc * (NN / NKC);      // 384 per chunk

    floatx4 zero = {0.f, 0.f, 0.f, 0.f};
    floatx4 acc[4][4];
#pragma unroll
    for (int i = 0; i < 4; ++i)
#pragma unroll
        for (int j = 0; j < 4; ++j) acc[i][j] = zero;

#pragma unroll 4
    for (int kk = 0; kk < 384; kk += 32) {
        short8 af[4], bf[4];
#pragma unroll
        for (int i = 0; i < 4; ++i)
            af[i] = ld8cvt(xb + (size_t)(tr * 128 + wr * 64 + i * 16 + lm) * NN
                           + n0 + kk + lk);
#pragma unroll
        for (int j = 0; j < 4; ++j)
            bf[j] = ld8cvt(xb + (size_t)(tc * 128 + wc * 64 + j * 16 + lm) * NN
                           + n0 + kk + lk);
#pragma unroll
        for (int i = 0; i < 4; ++i)
#pragma unroll
            for (int j = 0; j < 4; ++j)
                acc[i][j] = __builtin_amdgcn_mfma_f32_16x16x32_bf16(
                    af[i], bf[j], acc[i][j], 0, 0, 0);
    }
    float* Gf = Gpart + (size_t)blk * 16384;
#pragma unroll
    for (int i = 0; i < 4; ++i)
#pragma unroll
        for (int j = 0; j < 4; ++j)
#pragma unroll
            for (int rr = 0; rr < 4; ++rr)
                Gf[(size_t)(wr * 64 + i * 16 + lh * 4 + rr) * 128
                   + wc * 64 + j * 16 + lm] = acc[i][j][rr];
}

// ---------------------------------------------------------------------------
// gred: G[b][c][c'] = sum_kc Gpart  (fp32, 2 MB total). grid 512 x 256.
// ---------------------------------------------------------------------------
__global__ __launch_bounds__(256)
void gred_kernel(const float* __restrict__ Gpart, float* __restrict__ G)
{
    int idx = blockIdx.x * 256 + threadIdx.x;   // float4 id, 131072 total
    int b = idx >> 14;
    int fo = (idx & 16383) * 4;
    int c = fo >> 8;
    int cp = fo & 255;
    const float* src = Gpart + ((size_t)b * 32 + (size_t)((c >> 7) * 2 + (cp >> 7))) * 16384
                     + (size_t)(c & 127) * 128 + (cp & 127);
    floatx4 s = {0.f, 0.f, 0.f, 0.f};
#pragma unroll
    for (int k = 0; k < NKC; ++k)
        s += *(const floatx4*)(src + (size_t)k * 65536);
    *(floatx4*)(G + (size_t)b * 65536 + fo) = s;
}

// ---------------------------------------------------------------------------
// vecs: per-batch rank-1 vectors + C2. grid 8 x 256 (thread = channel c).
//   m = G q ; u2 = U sx ; va = VT sx ; um = U m
//   C2 = iv*((um + u1 s1 + (u2+N u1) s2)/N + w_b - mean) + beta
// ---------------------------------------------------------------------------
__global__ __launch_bounds__(256)
void vecs_kernel(const float* __restrict__ G, const float* __restrict__ U,
                 const float* __restrict__ VT, const float* __restrict__ qv,
                 const float* __restrict__ u1v, const float* __restrict__ sx,
                 const float* __restrict__ phi_b, const float* __restrict__ theta_b,
                 const float* __restrict__ w_b,
                 const float* __restrict__ gamma, const float* __restrict__ beta,
                 const float* __restrict__ mean, const float* __restrict__ var,
                 float* __restrict__ u2g, float* __restrict__ vag,
                 float* __restrict__ C2g)
{
    __shared__ float sxl[256], ql[256], ml[256];
    int b = blockIdx.x;
    int t = threadIdx.x;
    if (t < 64) {
        *(floatx4*)&sxl[t * 4] = *(const floatx4*)(sx + b * NC + t * 4);
        *(floatx4*)&ql[t * 4]  = *(const floatx4*)(qv + t * 4);
    }
    __syncthreads();

    float s1 = 0.f, s2 = 0.f;
#pragma unroll 8
    for (int k = 0; k < 256; ++k) s1 += sxl[k] * ql[k];
#pragma unroll 8
    for (int e = 0; e < 128; ++e) s2 += phi_b[e] * theta_b[e];

    // m[c] = sum_k G[c,k] q[k]
    {
        const float* Gr = G + (size_t)b * 65536 + (size_t)t * 256;
        float m = 0.f;
#pragma unroll
        for (int k = 0; k < 64; ++k) {
            floatx4 v = *(const floatx4*)(Gr + k * 4);
            m += v[0]*ql[k*4] + v[1]*ql[k*4+1] + v[2]*ql[k*4+2] + v[3]*ql[k*4+3];
        }
        ml[t] = m;
    }
    __syncthreads();

    float u2 = 0.f, um = 0.f, va = 0.f;
    {
        const float* Ur = U + (size_t)t * 256;
        const float* Vr = VT + (size_t)t * 256;
#pragma unroll
        for (int k = 0; k < 64; ++k) {
            floatx4 u = *(const floatx4*)(Ur + k * 4);
            floatx4 vv = *(const floatx4*)(Vr + k * 4);
            u2 += u[0]*sxl[k*4] + u[1]*sxl[k*4+1] + u[2]*sxl[k*4+2] + u[3]*sxl[k*4+3];
            um += u[0]*ml[k*4] + u[1]*ml[k*4+1] + u[2]*ml[k*4+2] + u[3]*ml[k*4+3];
            va += vv[0]*sxl[k*4] + vv[1]*sxl[k*4+1] + vv[2]*sxl[k*4+2] + vv[3]*sxl[k*4+3];
        }
    }
    float u1c = u1v[t];
    float c2raw = (um + u1c * s1 + (u2 + (float)NN * u1c) * s2) * (1.f / (float)NN);
    float iv = gamma[t] * rsqrtf(var[t] + BN_EPS);
    C2g[b * NC + t] = iv * (c2raw + w_b[t] - mean[t]) + beta[t];
    u2g[b * NC + t] = u2;
    vag[b * NC + t] = va;
}

// ---------------------------------------------------------------------------
// stageA: HT_b = VT . G_b  (G symmetric -> both operands row-contiguous).
// grid 32 = (b 8, tile 4), 256 thr. Output bf16 [c'][k'] (B-ready for stageB).
// ---------------------------------------------------------------------------
__global__ __launch_bounds__(256)
void stageA_kernel(const float* __restrict__ VT, const float* __restrict__ G,
                   short* __restrict__ HT)
{
    int blk = blockIdx.x;
    int b = blk >> 2;
    int tile = blk & 3, tr = tile >> 1, tc = tile & 1;
    int t = threadIdx.x, lane = t & 63, wave = t >> 6;
    int wr = wave >> 1, wc = wave & 1;
    int lm = lane & 15, lh = lane >> 4, lk = lh * 8;
    const float* Gb = G + (size_t)b * 65536;

    floatx4 zero = {0.f, 0.f, 0.f, 0.f};
    floatx4 acc[4][4];
#pragma unroll
    for (int i = 0; i < 4; ++i)
#pragma unroll
        for (int j = 0; j < 4; ++j) acc[i][j] = zero;

#pragma unroll 4
    for (int kk = 0; kk < 256; kk += 32) {
        short8 af[4], bf[4];
#pragma unroll
        for (int i = 0; i < 4; ++i)
            af[i] = ld8cvt(VT + (size_t)(tr * 128 + wr * 64 + i * 16 + lm) * NC + kk + lk);
#pragma unroll
        for (int j = 0; j < 4; ++j)
            bf[j] = ld8cvt(Gb + (size_t)(tc * 128 + wc * 64 + j * 16 + lm) * NC + kk + lk);
#pragma unroll
        for (int i = 0; i < 4; ++i)
#pragma unroll
            for (int j = 0; j < 4; ++j)
                acc[i][j] = __builtin_amdgcn_mfma_f32_16x16x32_bf16(
                    af[i], bf[j], acc[i][j], 0, 0, 0);
    }
    short* Hb = HT + (size_t)b * 65536;
#pragma unroll
    for (int i = 0; i < 4; ++i)
#pragma unroll
        for (int j = 0; j < 4; ++j)
#pragma unroll
            for (int rr = 0; rr < 4; ++rr)
                Hb[(size_t)(tr * 128 + wr * 64 + i * 16 + lh * 4 + rr) * NC
                   + tc * 128 + wc * 64 + j * 16 + lm] = f2s(acc[i][j][rr]);
}

// ---------------------------------------------------------------------------
// stageB: Qf[c,c'] = iv[c]/N * (sum_cp U[c,cp] HT[c',cp]
//                               + u1[c] va[c'] + (u2[c]+N u1[c]) vb[c'])
// grid 32 = (b 8, tile 4), 256 thr. Output bf16 QfB[b][c][c'] (A-ready).
// ---------------------------------------------------------------------------
__global__ __launch_bounds__(256)
void stageB_kernel(const float* __restrict__ U, const short* __restrict__ HT,
                   const float* __restrict__ u1v, const float* __restrict__ vbv,
                   const float* __restrict__ u2g, const float* __restrict__ vag,
                   const float* __restrict__ gamma, const float* __restrict__ var,
                   short* __restrict__ QfB)
{
    int blk = blockIdx.x;
    int b = blk >> 2;
    int tile = blk & 3, tr = tile >> 1, tc = tile & 1;
    int t = threadIdx.x, lane = t & 63, wave = t >> 6;
    int wr = wave >> 1, wc = wave & 1;
    int lm = lane & 15, lh = lane >> 4, lk = lh * 8;
    const short* Hb = HT + (size_t)b * 65536;

    floatx4 zero = {0.f, 0.f, 0.f, 0.f};
    floatx4 acc[4][4];
#pragma unroll
    for (int i = 0; i < 4; ++i)
#pragma unroll
        for (int j = 0; j < 4; ++j) acc[i][j] = zero;

#pragma unroll 4
    for (int kk = 0; kk < 256; kk += 32) {
        short8 af[4], bf[4];
#pragma unroll
        for (int i = 0; i < 4; ++i)
            af[i] = ld8cvt(U + (size_t)(tr * 128 + wr * 64 + i * 16 + lm) * NC + kk + lk);
#pragma unroll
        for (int j = 0; j < 4; ++j)
            bf[j] = *(const short8*)(Hb
                    + (size_t)(tc * 128 + wc * 64 + j * 16 + lm) * NC + kk + lk);
#pragma unroll
        for (int i = 0; i < 4; ++i)
#pragma unroll
            for (int j = 0; j < 4; ++j)
                acc[i][j] = __builtin_amdgcn_mfma_f32_16x16x32_bf16(
                    af[i], bf[j], acc[i][j], 0, 0, 0);
    }
#pragma unroll
    for (int i = 0; i < 4; ++i) {
#pragma unroll
        for (int rr = 0; rr < 4; ++rr) {
            int c = tr * 128 + wr * 64 + i * 16 + lh * 4 + rr;
            float u1c = u1v[c];
            float u2c = u2g[b * NC + c];
            float scl = gamma[c] * rsqrtf(var[c] + BN_EPS) * (1.f / (float)NN);
#pragma unroll
            for (int j = 0; j < 4; ++j) {
                int cp = tc * 128 + wc * 64 + j * 16 + lm;
                float v = acc[i][j][rr] + u1c * vag[b * NC + cp]
                        + (u2c + (float)NN * u1c) * vbv[cp];
                QfB[(size_t)b * 65536 + (size_t)c * NC + cp] = f2s(v * scl);
            }
        }
    }
}

// ---------------------------------------------------------------------------
// out: out[c,n] = sum_c' Qf[c,c'] x[c',n] + C2[c] + x[c,n]
// grid (32 n-tiles x 8 b) = 256 blocks, 512 thr = 8 waves (4c x 2n).
// A direct from QfB (L2/L3-hot); x via LDS transpose with T14 reg-prefetch.
// ---------------------------------------------------------------------------
__global__ __launch_bounds__(512, 2)
void out_kernel(const short* __restrict__ QfB, const float* __restrict__ C2g,
                const float* __restrict__ x, float* __restrict__ out)
{
    __shared__ short Xs[96][72];
    int blk = blockIdx.x;
    int b = blk >> 5;
    int n0 = (blk & 31) * 96;
    int t = threadIdx.x, lane = t & 63, wave = t >> 6;
    int lm = lane & 15, lh = lane >> 4, lk = lh * 8;
    int wr = wave >> 1, wc = wave & 1;
    const float* xb = x + (size_t)b * NC * NN;
    const short* Qb = QfB + (size_t)b * 65536;

    floatx4 zero = {0.f, 0.f, 0.f, 0.f};
    floatx4 acc[4][3];
#pragma unroll
    for (int i = 0; i < 4; ++i)
#pragma unroll
        for (int j = 0; j < 3; ++j) acc[i][j] = zero;

    int sn = t % 96, cgp = t / 96;   // valid for t < 384
    float xf[16];
    if (t < 384) {
#pragma unroll
        for (int j = 0; j < 16; ++j)
            xf[j] = xb[(size_t)(cgp * 16 + j) * NN + n0 + sn];
    }

#pragma unroll
    for (int kt = 0; kt < NC; kt += 64) {
        __syncthreads();
        short8 af2[2][4];
#pragma unroll
        for (int h = 0; h < 2; ++h)
#pragma unroll
            for (int i = 0; i < 4; ++i)
                af2[h][i] = *(const short8*)(Qb
                        + (size_t)(wr * 64 + i * 16 + lm) * 256 + kt + h * 32 + lk);
        if (t < 384) {
            short8 s0, s1;
#pragma unroll
            for (int j = 0; j < 8; ++j) {
                s0[j] = f2s(xf[j]);
                s1[j] = f2s(xf[8 + j]);
            }
            *(short8*)&Xs[sn][cgp * 16]     = s0;
            *(short8*)&Xs[sn][cgp * 16 + 8] = s1;
        }
        __syncthreads();
        if (t < 384 && kt < NC - 64) {
#pragma unroll
            for (int j = 0; j < 16; ++j)
                xf[j] = xb[(size_t)(kt + 64 + cgp * 16 + j) * NN + n0 + sn];
        }
#pragma unroll
        for (int h = 0; h < 2; ++h) {
            short8 bfr[3];
#pragma unroll
            for (int j = 0; j < 3; ++j)
                bfr[j] = *(const short8*)&Xs[wc * 48 + j * 16 + lm][h * 32 + lk];
#pragma unroll
            for (int i = 0; i < 4; ++i)
#pragma unroll
                for (int j = 0; j < 3; ++j)
                    acc[i][j] = __builtin_amdgcn_mfma_f32_16x16x32_bf16(
                        af2[h][i], bfr[j], acc[i][j], 0, 0, 0);
        }
    }

    float* Cf = out + (size_t)b * NC * NN;
#pragma unroll
    for (int i = 0; i < 4; ++i) {
#pragma unroll
        for (int rr = 0; rr < 4; ++rr) {
            int c = wr * 64 + i * 16 + lh * 4 + rr;
            float c2 = C2g[b * NC + c];
#pragma unroll
            for (int j = 0; j < 3; ++j) {
                size_t idx = (size_t)c * NN + n0 + wc * 48 + j * 16 + lm;
                Cf[idx] = acc[i][j][rr] + c2 + xb[idx];
            }
        }
    }
}

extern "C" void kernel_launch(void* const* d_in, const int* in_sizes, int n_in,
                              void* d_out, int out_size, void* d_ws, size_t ws_size,
                              hipStream_t stream)
{
    const float* x       = (const float*)d_in[0];
    const float* g_w     = (const float*)d_in[1];
    const float* g_b     = (const float*)d_in[2];
    const float* theta_w = (const float*)d_in[3];
    const float* theta_b = (const float*)d_in[4];
    const float* phi_w   = (const float*)d_in[5];
    const float* phi_b   = (const float*)d_in[6];
    const float* w_w     = (const float*)d_in[7];
    const float* w_b     = (const float*)d_in[8];
    const float* gamma   = (const float*)d_in[9];
    const float* beta    = (const float*)d_in[10];
    const float* mean    = (const float*)d_in[11];
    const float* var     = (const float*)d_in[12];
    (void)in_sizes; (void)n_in; (void)out_size; (void)ws_size;

    char* w = (char*)d_ws;
    float* sx    = (float*)w; w += (size_t)NB * NC * 4;               // 8 KB
    float* C2g   = (float*)w; w += (size_t)NB * NC * 4;               // 8 KB
    float* u2g   = (float*)w; w += (size_t)NB * NC * 4;               // 8 KB
    float* vag   = (float*)w; w += (size_t)NB * NC * 4;               // 8 KB
    float* qv    = (float*)w; w += (size_t)NC * 4;                    // 1 KB
    float* u1v   = (float*)w; w += (size_t)NC * 4;                    // 1 KB
    float* vbv   = (float*)w; w += (size_t)NC * 4;                    // 1 KB
    w = (char*)(((size_t)w + 255) & ~(size_t)255);
    float* U     = (float*)w; w += (size_t)NC * NC * 4;               // 256 KB
    float* VT    = (float*)w; w += (size_t)NC * NC * 4;               // 256 KB
    float* G     = (float*)w; w += (size_t)NB * NC * NC * 4;          // 2 MB
    float* Gpart = (float*)w; w += (size_t)NB * NKC * 4 * 16384 * 4;  // 16 MB
    short* HT    = (short*)w; w += (size_t)NB * NC * NC * 2;          // 1 MB
    short* QfB   = (short*)w; w += (size_t)NB * NC * NC * 2;          // 1 MB

    prep_kernel<<<dim3(265), dim3(256), 0, stream>>>(
        x, g_w, g_b, theta_w, theta_b, phi_w, phi_b, w_w,
        sx, U, VT, qv, u1v, vbv);

    gpart_kernel<<<dim3(NB * NKC * 4), dim3(256), 0, stream>>>(x, Gpart);

    gred_kernel<<<dim3(512), dim3(256), 0, stream>>>(Gpart, G);

    vecs_kernel<<<dim3(NB), dim3(256), 0, stream>>>(
        G, U, VT, qv, u1v, sx, phi_b, theta_b, w_b,
        gamma, beta, mean, var, u2g, vag, C2g);

    stageA_kernel<<<dim3(NB * 4), dim3(256), 0, stream>>>(VT, G, HT);

    stageB_kernel<<<dim3(NB * 4), dim3(256), 0, stream>>>(
        U, HT, u1v, vbv, u2g, vag, gamma, var, QfB);

    out_kernel<<<dim3(256), dim3(512), 0, stream>>>(QfB, C2g, x, (float*)d_out);
}

// Round 6
// 207.969 us; speedup vs baseline: 1.1369x; 1.0804x over previous
//
#include <hip/hip_runtime.h>
#include <hip/hip_bf16.h>
#include <cstddef>

typedef __attribute__((ext_vector_type(8))) short short8;
typedef __attribute__((ext_vector_type(4))) short short4v;
typedef __attribute__((ext_vector_type(4))) float floatx4;
typedef __hip_bfloat16 bf16;

#define NB 8
#define NC 256
#define ND 128
#define NN 3072
#define NKC 8             /* split-K chunks for G = x x^T */
#define BN_EPS 1e-5f

static __device__ __forceinline__ short f2s(float v) {
    bf16 h = __float2bfloat16(v);
    return *reinterpret_cast<short*>(&h);
}

// load 8 consecutive fp32, convert to bf16 short8 (MFMA operand)
static __device__ __forceinline__ short8 ld8cvt(const float* p) {
    floatx4 a = *(const floatx4*)p, b = *(const floatx4*)(p + 4);
    short8 r;
    r[0] = f2s(a[0]); r[1] = f2s(a[1]); r[2] = f2s(a[2]); r[3] = f2s(a[3]);
    r[4] = f2s(b[0]); r[5] = f2s(b[1]); r[6] = f2s(b[2]); r[7] = f2s(b[3]);
    return r;
}

// ---------------------------------------------------------------------------
// front: ONE wide launch, grid 521.
//   blk 0..255   -> Gpart tiles (G = x x^T split-K, no LDS, direct-global)
//   blk 256..511 -> sx[b][c] = sum_n x[b,c,n]
//   blk 512..515 -> U = w_w . g_w (256x256 fp32)
//   blk 516..519 -> VT[c'][k] = sum_e theta_w[e,c'] phi_w[e,k]
//   blk 520      -> q = phi_w^T theta_b ; u1 = w_w g_b ; vb = theta_w^T phi_b
// ---------------------------------------------------------------------------
__global__ __launch_bounds__(256)
void front_kernel(const float* __restrict__ x,
                  const float* __restrict__ g_w, const float* __restrict__ g_b,
                  const float* __restrict__ theta_w, const float* __restrict__ theta_b,
                  const float* __restrict__ phi_w, const float* __restrict__ phi_b,
                  const float* __restrict__ w_w,
                  float* __restrict__ Gpart, float* __restrict__ sx,
                  float* __restrict__ U, float* __restrict__ VT,
                  float* __restrict__ qv, float* __restrict__ u1v,
                  float* __restrict__ vbv)
{
    __shared__ short TA[128][136];
    __shared__ short TB[128][136];
    int blk = blockIdx.x;
    int t = threadIdx.x;

    if (blk < 256) {          // ---- Gpart
        int tile = blk & 3;
        int kc = (blk >> 2) & 7;
        int b = blk >> 5;
        int tr = tile >> 1, tc = tile & 1;
        int lane = t & 63, wave = t >> 6;
        int wr = wave >> 1, wc = wave & 1;
        int lm = lane & 15, lh = lane >> 4, lk = lh * 8;
        const float* xb = x + (size_t)b * NC * NN;
        int n0 = kc * (NN / NKC);      // 384 per chunk

        floatx4 zero = {0.f, 0.f, 0.f, 0.f};
        floatx4 acc[4][4];
#pragma unroll
        for (int i = 0; i < 4; ++i)
#pragma unroll
            for (int j = 0; j < 4; ++j) acc[i][j] = zero;

#pragma unroll 4
        for (int kk = 0; kk < 384; kk += 32) {
            short8 af[4], bf[4];
#pragma unroll
            for (int i = 0; i < 4; ++i)
                af[i] = ld8cvt(xb + (size_t)(tr * 128 + wr * 64 + i * 16 + lm) * NN
                               + n0 + kk + lk);
#pragma unroll
            for (int j = 0; j < 4; ++j)
                bf[j] = ld8cvt(xb + (size_t)(tc * 128 + wc * 64 + j * 16 + lm) * NN
                               + n0 + kk + lk);
#pragma unroll
            for (int i = 0; i < 4; ++i)
#pragma unroll
                for (int j = 0; j < 4; ++j)
                    acc[i][j] = __builtin_amdgcn_mfma_f32_16x16x32_bf16(
                        af[i], bf[j], acc[i][j], 0, 0, 0);
        }
        float* Gf = Gpart + (size_t)blk * 16384;
#pragma unroll
        for (int i = 0; i < 4; ++i)
#pragma unroll
            for (int j = 0; j < 4; ++j)
#pragma unroll
                for (int rr = 0; rr < 4; ++rr)
                    Gf[(size_t)(wr * 64 + i * 16 + lh * 4 + rr) * 128
                       + wc * 64 + j * 16 + lm] = acc[i][j][rr];
        return;
    }
    if (blk < 512) {          // ---- sx
        int bs = blk - 256;
        int b = bs >> 5;
        int c0 = (bs & 31) * 8;
        int r = t >> 5;
        int w32 = t & 31;
        const float* xr = x + ((size_t)b * NC + c0 + r) * NN;
        float s = 0.f;
#pragma unroll
        for (int k = 0; k < 24; ++k) {
            floatx4 v = *(const floatx4*)(xr + (size_t)(w32 + k * 32) * 4);
            s += v[0] + v[1] + v[2] + v[3];
        }
#pragma unroll
        for (int off = 16; off; off >>= 1) s += __shfl_down(s, off, 32);
        if (w32 == 0) sx[b * NC + c0 + r] = s;
        return;
    }
    if (blk == 520) {         // ---- small vectors
        int c = t;
        float s_q = 0.f, s_vb = 0.f, s_u1 = 0.f;
#pragma unroll
        for (int e = 0; e < 128; ++e) {
            s_q  += phi_w[(size_t)e * NC + c] * theta_b[e];
            s_vb += theta_w[(size_t)e * NC + c] * phi_b[e];
        }
        const float* wr_ = w_w + (size_t)c * ND;
#pragma unroll
        for (int d = 0; d < 32; ++d) {
            floatx4 v = *(const floatx4*)(wr_ + d * 4);
            floatx4 gb = *(const floatx4*)(g_b + d * 4);
            s_u1 += v[0]*gb[0] + v[1]*gb[1] + v[2]*gb[2] + v[3]*gb[3];
        }
        qv[c] = s_q; vbv[c] = s_vb; u1v[c] = s_u1;
        return;
    }

    int lane = t & 63, wave = t >> 6;
    int lm = lane & 15, lh = lane >> 4, lk = lh * 8;
    int wr = wave >> 1, wc = wave & 1;
    floatx4 zero = {0.f, 0.f, 0.f, 0.f};
    floatx4 acc[4][4];
#pragma unroll
    for (int i = 0; i < 4; ++i)
#pragma unroll
        for (int j = 0; j < 4; ++j) acc[i][j] = zero;

    if (blk < 516) {          // ---- U tile
        int ti = blk - 512, tr = ti >> 1, tc = ti & 1;
#pragma unroll
        for (int p = 0; p < 8; ++p) {
            int idx = p * 256 + t;
            int d = idx >> 4;
            int cg = (idx & 15) * 8;
            floatx4 v0 = *(const floatx4*)(g_w + (size_t)d * NC + tc * 128 + cg);
            floatx4 v1 = *(const floatx4*)(g_w + (size_t)d * NC + tc * 128 + cg + 4);
#pragma unroll
            for (int j = 0; j < 4; ++j) {
                TB[cg + j][d] = f2s(v0[j]);
                TB[cg + 4 + j][d] = f2s(v1[j]);
            }
        }
        __syncthreads();
#pragma unroll
        for (int kk = 0; kk < 128; kk += 32) {
            short8 af[4], bf[4];
#pragma unroll
            for (int i = 0; i < 4; ++i)
                af[i] = ld8cvt(w_w + (size_t)(tr * 128 + wr * 64 + i * 16 + lm) * ND + kk + lk);
#pragma unroll
            for (int j = 0; j < 4; ++j)
                bf[j] = *(const short8*)&TB[wc * 64 + j * 16 + lm][kk + lk];
#pragma unroll
            for (int i = 0; i < 4; ++i)
#pragma unroll
                for (int j = 0; j < 4; ++j)
                    acc[i][j] = __builtin_amdgcn_mfma_f32_16x16x32_bf16(
                        af[i], bf[j], acc[i][j], 0, 0, 0);
        }
#pragma unroll
        for (int i = 0; i < 4; ++i)
#pragma unroll
            for (int j = 0; j < 4; ++j)
#pragma unroll
                for (int rr = 0; rr < 4; ++rr)
                    U[(size_t)(tr * 128 + wr * 64 + i * 16 + lh * 4 + rr) * NC
                      + tc * 128 + wc * 64 + j * 16 + lm] = acc[i][j][rr];
    } else {                  // ---- VT tile
        int ti = blk - 516, tr = ti >> 1, tc = ti & 1;
#pragma unroll
        for (int p = 0; p < 8; ++p) {
            int idx = p * 256 + t;
            int e = idx >> 4;
            int cg = (idx & 15) * 8;
            floatx4 a0 = *(const floatx4*)(theta_w + (size_t)e * NC + tr * 128 + cg);
            floatx4 a1 = *(const floatx4*)(theta_w + (size_t)e * NC + tr * 128 + cg + 4);
            floatx4 b0 = *(const floatx4*)(phi_w + (size_t)e * NC + tc * 128 + cg);
            floatx4 b1 = *(const floatx4*)(phi_w + (size_t)e * NC + tc * 128 + cg + 4);
#pragma unroll
            for (int j = 0; j < 4; ++j) {
                TA[cg + j][e] = f2s(a0[j]); TA[cg + 4 + j][e] = f2s(a1[j]);
                TB[cg + j][e] = f2s(b0[j]); TB[cg + 4 + j][e] = f2s(b1[j]);
            }
        }
        __syncthreads();
#pragma unroll
        for (int kk = 0; kk < 128; kk += 32) {
            short8 af[4], bf[4];
#pragma unroll
            for (int i = 0; i < 4; ++i)
                af[i] = *(const short8*)&TA[wr * 64 + i * 16 + lm][kk + lk];
#pragma unroll
            for (int j = 0; j < 4; ++j)
                bf[j] = *(const short8*)&TB[wc * 64 + j * 16 + lm][kk + lk];
#pragma unroll
            for (int i = 0; i < 4; ++i)
#pragma unroll
                for (int j = 0; j < 4; ++j)
                    acc[i][j] = __builtin_amdgcn_mfma_f32_16x16x32_bf16(
                        af[i], bf[j], acc[i][j], 0, 0, 0);
        }
#pragma unroll
        for (int i = 0; i < 4; ++i)
#pragma unroll
            for (int j = 0; j < 4; ++j)
#pragma unroll
                for (int rr = 0; rr < 4; ++rr)
                    VT[(size_t)(tr * 128 + wr * 64 + i * 16 + lh * 4 + rr) * NC
                       + tc * 128 + wc * 64 + j * 16 + lm] = acc[i][j][rr];
    }
}

// ---------------------------------------------------------------------------
// gred_uva: blk 0..511 -> G[b][c][c'] = sum_kc Gpart (wide, BW-bound)
//           blk 512..519 -> per-batch u2 = U sx, va = VT sx (overlaps gred)
// ---------------------------------------------------------------------------
__global__ __launch_bounds__(256)
void gred_uva_kernel(const float* __restrict__ Gpart, const float* __restrict__ U,
                     const float* __restrict__ VT, const float* __restrict__ sx,
                     float* __restrict__ G, float* __restrict__ u2g,
                     float* __restrict__ vag)
{
    __shared__ float sxl[256];
    int blk = blockIdx.x;
    int t = threadIdx.x;
    if (blk < 512) {
        int idx = blk * 256 + t;            // float4 id, 131072 total
        int b = idx >> 14;
        int fo = (idx & 16383) * 4;
        int c = fo >> 8;
        int cp = fo & 255;
        const float* src = Gpart + ((size_t)b * 32 + (size_t)((c >> 7) * 2 + (cp >> 7))) * 16384
                         + (size_t)(c & 127) * 128 + (cp & 127);
        floatx4 s = {0.f, 0.f, 0.f, 0.f};
#pragma unroll
        for (int k = 0; k < NKC; ++k)
            s += *(const floatx4*)(src + (size_t)k * 65536);
        *(floatx4*)(G + (size_t)b * 65536 + fo) = s;
        return;
    }
    int b = blk - 512;
    if (t < 64) *(floatx4*)&sxl[t * 4] = *(const floatx4*)(sx + b * NC + t * 4);
    __syncthreads();
    float u2 = 0.f, va = 0.f;
    const float* Ur = U + (size_t)t * 256;
    const float* Vr = VT + (size_t)t * 256;
#pragma unroll
    for (int k = 0; k < 64; ++k) {
        floatx4 u = *(const floatx4*)(Ur + k * 4);
        floatx4 vv = *(const floatx4*)(Vr + k * 4);
        u2 += u[0]*sxl[k*4] + u[1]*sxl[k*4+1] + u[2]*sxl[k*4+2] + u[3]*sxl[k*4+3];
        va += vv[0]*sxl[k*4] + vv[1]*sxl[k*4+1] + vv[2]*sxl[k*4+2] + vv[3]*sxl[k*4+3];
    }
    u2g[b * NC + t] = u2;
    vag[b * NC + t] = va;
}

// ---------------------------------------------------------------------------
// qf: blk 0..31 -> fused Qf tile, via T = U.G (LDS bf16) then Qf = T.VT^T
//     (re-association of R5's stageA+stageB; G symmetric -> all row-contig)
//     Qf[c,c'] = iv[c]/N * (sum_k T[c,k] VT[c',k] + u1[c]va[c'] + (u2+Nu1)vb[c'])
//     blk 32..39 -> per-batch C2 (m = Gq, um = Um, + rank-1 corrections)
// ---------------------------------------------------------------------------
union QSm {
    short T[128][264];                        // 67.6 KB
    struct { float ql[256]; float sxl[256]; float ml[256]; } v;
};

__global__ __launch_bounds__(256)
void qf_kernel(const float* __restrict__ G, const float* __restrict__ U,
               const float* __restrict__ VT, const float* __restrict__ qv,
               const float* __restrict__ u1v, const float* __restrict__ vbv,
               const float* __restrict__ u2g, const float* __restrict__ vag,
               const float* __restrict__ sx,
               const float* __restrict__ phi_b, const float* __restrict__ theta_b,
               const float* __restrict__ w_b,
               const float* __restrict__ gamma, const float* __restrict__ beta,
               const float* __restrict__ mean, const float* __restrict__ var,
               short* __restrict__ QfB, float* __restrict__ C2g)
{
    __shared__ QSm sm;
    int blk = blockIdx.x;
    int t = threadIdx.x;

    if (blk >= 32) {          // ---- C2 blocks
        int b = blk - 32;
        if (t < 64) {
            *(floatx4*)&sm.v.ql[t * 4]  = *(const floatx4*)(qv + t * 4);
            *(floatx4*)&sm.v.sxl[t * 4] = *(const floatx4*)(sx + b * NC + t * 4);
        }
        __syncthreads();
        float s1 = 0.f, s2 = 0.f;
#pragma unroll 8
        for (int k = 0; k < 256; ++k) s1 += sm.v.sxl[k] * sm.v.ql[k];
#pragma unroll 8
        for (int e = 0; e < 128; ++e) s2 += phi_b[e] * theta_b[e];
        {   // m = G q
            const float* Gr = G + (size_t)b * 65536 + (size_t)t * 256;
            float m = 0.f;
#pragma unroll
            for (int k = 0; k < 64; ++k) {
                floatx4 v = *(const floatx4*)(Gr + k * 4);
                m += v[0]*sm.v.ql[k*4] + v[1]*sm.v.ql[k*4+1]
                   + v[2]*sm.v.ql[k*4+2] + v[3]*sm.v.ql[k*4+3];
            }
            sm.v.ml[t] = m;
        }
        __syncthreads();
        float um = 0.f;
        const float* Ur = U + (size_t)t * 256;
#pragma unroll
        for (int k = 0; k < 64; ++k) {
            floatx4 u = *(const floatx4*)(Ur + k * 4);
            um += u[0]*sm.v.ml[k*4] + u[1]*sm.v.ml[k*4+1]
                + u[2]*sm.v.ml[k*4+2] + u[3]*sm.v.ml[k*4+3];
        }
        float u1c = u1v[t];
        float u2c = u2g[b * NC + t];
        float c2raw = (um + u1c * s1 + (u2c + (float)NN * u1c) * s2) * (1.f / (float)NN);
        float iv = gamma[t] * rsqrtf(var[t] + BN_EPS);
        C2g[b * NC + t] = iv * (c2raw + w_b[t] - mean[t]) + beta[t];
        return;
    }

    // ---- Qf tile blocks
    int b = blk >> 2;
    int tile = blk & 3, tr = tile >> 1, tc = tile & 1;
    int lane = t & 63, wave = t >> 6;
    int wr = wave >> 1, wc = wave & 1;
    int lm = lane & 15, lh = lane >> 4, lk = lh * 8;
    const float* Gb = G + (size_t)b * 65536;
    floatx4 zero = {0.f, 0.f, 0.f, 0.f};

    // T = U[tr-half] . G  (two k-half passes, acc[4][4] each)
#pragma unroll
    for (int h2 = 0; h2 < 2; ++h2) {
        floatx4 acc[4][4];
#pragma unroll
        for (int i = 0; i < 4; ++i)
#pragma unroll
            for (int j = 0; j < 4; ++j) acc[i][j] = zero;
#pragma unroll 4
        for (int kk = 0; kk < 256; kk += 32) {      // K = cp
            short8 af[4], bf[4];
#pragma unroll
            for (int i = 0; i < 4; ++i)
                af[i] = ld8cvt(U + (size_t)(tr * 128 + wr * 64 + i * 16 + lm) * NC + kk + lk);
#pragma unroll
            for (int j = 0; j < 4; ++j)
                bf[j] = ld8cvt(Gb + (size_t)(h2 * 128 + wc * 64 + j * 16 + lm) * NC + kk + lk);
#pragma unroll
            for (int i = 0; i < 4; ++i)
#pragma unroll
                for (int j = 0; j < 4; ++j)
                    acc[i][j] = __builtin_amdgcn_mfma_f32_16x16x32_bf16(
                        af[i], bf[j], acc[i][j], 0, 0, 0);
        }
#pragma unroll
        for (int i = 0; i < 4; ++i)
#pragma unroll
            for (int j = 0; j < 4; ++j)
#pragma unroll
                for (int rr = 0; rr < 4; ++rr)
                    sm.T[wr * 64 + i * 16 + lh * 4 + rr]
                        [h2 * 128 + wc * 64 + j * 16 + lm] = f2s(acc[i][j][rr]);
    }
    __syncthreads();

    // Qf = T . VT^T  (K = k = 256, A from LDS, B from global VT)
    floatx4 acc2[4][4];
#pragma unroll
    for (int i = 0; i < 4; ++i)
#pragma unroll
        for (int j = 0; j < 4; ++j) acc2[i][j] = zero;
#pragma unroll 4
    for (int kk = 0; kk < 256; kk += 32) {
        short8 af[4], bf[4];
#pragma unroll
        for (int i = 0; i < 4; ++i)
            af[i] = *(const short8*)&sm.T[wr * 64 + i * 16 + lm][kk + lk];
#pragma unroll
        for (int j = 0; j < 4; ++j)
            bf[j] = ld8cvt(VT + (size_t)(tc * 128 + wc * 64 + j * 16 + lm) * NC + kk + lk);
#pragma unroll
        for (int i = 0; i < 4; ++i)
#pragma unroll
            for (int j = 0; j < 4; ++j)
                acc2[i][j] = __builtin_amdgcn_mfma_f32_16x16x32_bf16(
                    af[i], bf[j], acc2[i][j], 0, 0, 0);
    }
#pragma unroll
    for (int i = 0; i < 4; ++i) {
#pragma unroll
        for (int rr = 0; rr < 4; ++rr) {
            int c = tr * 128 + wr * 64 + i * 16 + lh * 4 + rr;
            float u1c = u1v[c];
            float u2c = u2g[b * NC + c];
            float scl = gamma[c] * rsqrtf(var[c] + BN_EPS) * (1.f / (float)NN);
#pragma unroll
            for (int j = 0; j < 4; ++j) {
                int cp = tc * 128 + wc * 64 + j * 16 + lm;
                float v = acc2[i][j][rr] + u1c * vag[b * NC + cp]
                        + (u2c + (float)NN * u1c) * vbv[cp];
                QfB[(size_t)b * 65536 + (size_t)c * NC + cp] = f2s(v * scl);
            }
        }
    }
}

// ---------------------------------------------------------------------------
// out: out[c,n] = sum_c' Qf[c,c'] x[c',n] + C2[c] + x[c,n]
// grid (32 n-tiles x 8 b) = 256 blocks, 512 thr = 8 waves (4c x 2n).
// A direct from QfB (L2/L3-hot); x via LDS transpose with T14 reg-prefetch.
// ---------------------------------------------------------------------------
__global__ __launch_bounds__(512, 2)
void out_kernel(const short* __restrict__ QfB, const float* __restrict__ C2g,
                const float* __restrict__ x, float* __restrict__ out)
{
    __shared__ short Xs[96][72];
    int blk = blockIdx.x;
    int b = blk >> 5;
    int n0 = (blk & 31) * 96;
    int t = threadIdx.x, lane = t & 63, wave = t >> 6;
    int lm = lane & 15, lh = lane >> 4, lk = lh * 8;
    int wr = wave >> 1, wc = wave & 1;
    const float* xb = x + (size_t)b * NC * NN;
    const short* Qb = QfB + (size_t)b * 65536;

    floatx4 zero = {0.f, 0.f, 0.f, 0.f};
    floatx4 acc[4][3];
#pragma unroll
    for (int i = 0; i < 4; ++i)
#pragma unroll
        for (int j = 0; j < 3; ++j) acc[i][j] = zero;

    int sn = t % 96, cgp = t / 96;   // valid for t < 384
    float xf[16];
    if (t < 384) {
#pragma unroll
        for (int j = 0; j < 16; ++j)
            xf[j] = xb[(size_t)(cgp * 16 + j) * NN + n0 + sn];
    }

#pragma unroll
    for (int kt = 0; kt < NC; kt += 64) {
        __syncthreads();
        short8 af2[2][4];
#pragma unroll
        for (int h = 0; h < 2; ++h)
#pragma unroll
            for (int i = 0; i < 4; ++i)
                af2[h][i] = *(const short8*)(Qb
                        + (size_t)(wr * 64 + i * 16 + lm) * 256 + kt + h * 32 + lk);
        if (t < 384) {
            short8 s0, s1;
#pragma unroll
            for (int j = 0; j < 8; ++j) {
                s0[j] = f2s(xf[j]);
                s1[j] = f2s(xf[8 + j]);
            }
            *(short8*)&Xs[sn][cgp * 16]     = s0;
            *(short8*)&Xs[sn][cgp * 16 + 8] = s1;
        }
        __syncthreads();
        if (t < 384 && kt < NC - 64) {
#pragma unroll
            for (int j = 0; j < 16; ++j)
                xf[j] = xb[(size_t)(kt + 64 + cgp * 16 + j) * NN + n0 + sn];
        }
#pragma unroll
        for (int h = 0; h < 2; ++h) {
            short8 bfr[3];
#pragma unroll
            for (int j = 0; j < 3; ++j)
                bfr[j] = *(const short8*)&Xs[wc * 48 + j * 16 + lm][h * 32 + lk];
#pragma unroll
            for (int i = 0; i < 4; ++i)
#pragma unroll
                for (int j = 0; j < 3; ++j)
                    acc[i][j] = __builtin_amdgcn_mfma_f32_16x16x32_bf16(
                        af2[h][i], bfr[j], acc[i][j], 0, 0, 0);
        }
    }

    float* Cf = out + (size_t)b * NC * NN;
#pragma unroll
    for (int i = 0; i < 4; ++i) {
#pragma unroll
        for (int rr = 0; rr < 4; ++rr) {
            int c = wr * 64 + i * 16 + lh * 4 + rr;
            float c2 = C2g[b * NC + c];
#pragma unroll
            for (int j = 0; j < 3; ++j) {
                size_t idx = (size_t)c * NN + n0 + wc * 48 + j * 16 + lm;
                Cf[idx] = acc[i][j][rr] + c2 + xb[idx];
            }
        }
    }
}

extern "C" void kernel_launch(void* const* d_in, const int* in_sizes, int n_in,
                              void* d_out, int out_size, void* d_ws, size_t ws_size,
                              hipStream_t stream)
{
    const float* x       = (const float*)d_in[0];
    const float* g_w     = (const float*)d_in[1];
    const float* g_b     = (const float*)d_in[2];
    const float* theta_w = (const float*)d_in[3];
    const float* theta_b = (const float*)d_in[4];
    const float* phi_w   = (const float*)d_in[5];
    const float* phi_b   = (const float*)d_in[6];
    const float* w_w     = (const float*)d_in[7];
    const float* w_b     = (const float*)d_in[8];
    const float* gamma   = (const float*)d_in[9];
    const float* beta    = (const float*)d_in[10];
    const float* mean    = (const float*)d_in[11];
    const float* var     = (const float*)d_in[12];
    (void)in_sizes; (void)n_in; (void)out_size; (void)ws_size;

    char* w = (char*)d_ws;
    float* sx    = (float*)w; w += (size_t)NB * NC * 4;               // 8 KB
    float* C2g   = (float*)w; w += (size_t)NB * NC * 4;               // 8 KB
    float* u2g   = (float*)w; w += (size_t)NB * NC * 4;               // 8 KB
    float* vag   = (float*)w; w += (size_t)NB * NC * 4;               // 8 KB
    float* qv    = (float*)w; w += (size_t)NC * 4;                    // 1 KB
    float* u1v   = (float*)w; w += (size_t)NC * 4;                    // 1 KB
    float* vbv   = (float*)w; w += (size_t)NC * 4;                    // 1 KB
    w = (char*)(((size_t)w + 255) & ~(size_t)255);
    float* U     = (float*)w; w += (size_t)NC * NC * 4;               // 256 KB
    float* VT    = (float*)w; w += (size_t)NC * NC * 4;               // 256 KB
    float* G     = (float*)w; w += (size_t)NB * NC * NC * 4;          // 2 MB
    float* Gpart = (float*)w; w += (size_t)NB * NKC * 4 * 16384 * 4;  // 16 MB
    short* QfB   = (short*)w; w += (size_t)NB * NC * NC * 2;          // 1 MB

    front_kernel<<<dim3(521), dim3(256), 0, stream>>>(
        x, g_w, g_b, theta_w, theta_b, phi_w, phi_b, w_w,
        Gpart, sx, U, VT, qv, u1v, vbv);

    gred_uva_kernel<<<dim3(520), dim3(256), 0, stream>>>(
        Gpart, U, VT, sx, G, u2g, vag);

    qf_kernel<<<dim3(40), dim3(256), 0, stream>>>(
        G, U, VT, qv, u1v, vbv, u2g, vag, sx,
        phi_b, theta_b, w_b, gamma, beta, mean, var, QfB, C2g);

    out_kernel<<<dim3(256), dim3(512), 0, stream>>>(QfB, C2g, x, (float*)d_out);
}

// Round 7
// 187.085 us; speedup vs baseline: 1.2638x; 1.1116x over previous
//
#include <hip/hip_runtime.h>
#include <hip/hip_bf16.h>
#include <cstddef>

typedef __attribute__((ext_vector_type(8))) short short8;
typedef __attribute__((ext_vector_type(4))) short short4v;
typedef __attribute__((ext_vector_type(4))) float floatx4;
typedef __hip_bfloat16 bf16;

#define NB 8
#define NC 256
#define ND 128
#define NN 3072
#define NCH 32            /* n-chunks for G = x x^T (96 each) */
#define BN_EPS 1e-5f

static __device__ __forceinline__ short f2s(float v) {
    bf16 h = __float2bfloat16(v);
    return *reinterpret_cast<short*>(&h);
}
static __device__ __forceinline__ float s2f(short s) {
    unsigned int u = ((unsigned int)(unsigned short)s) << 16;
    return __uint_as_float(u);
}
// load 8 consecutive fp32, convert to bf16 short8 (MFMA operand)
static __device__ __forceinline__ short8 ld8cvt(const float* p) {
    floatx4 a = *(const floatx4*)p, b = *(const floatx4*)(p + 4);
    short8 r;
    r[0] = f2s(a[0]); r[1] = f2s(a[1]); r[2] = f2s(a[2]); r[3] = f2s(a[3]);
    r[4] = f2s(b[0]); r[5] = f2s(b[1]); r[6] = f2s(b[2]); r[7] = f2s(b[3]);
    return r;
}

// ---------------------------------------------------------------------------
// front: grid 384 x 512 thr.
//   blk 0..255  -> G-partial: block (b = blk>>5, chunk = blk&31) stages
//     x[256 c][96 n] -> LDS bf16 ONCE (x read exactly once), computes the
//     full 256x256 partial X.X^T from LDS (8 waves x 128x64 tiles), stores
//     Gpart bf16 [blk][256*256].
//   blk 256..383 -> sx[b][c] = sum_n x[b,c,n]  (16 rows x 32 lanes)
// ---------------------------------------------------------------------------
__global__ __launch_bounds__(512, 2)
void front_kernel(const float* __restrict__ x, short* __restrict__ GpartS,
                  float* __restrict__ sx)
{
    __shared__ short Xs[256][104];   // 53.2 KB
    int blk = blockIdx.x;
    int t = threadIdx.x;

    if (blk >= 256) {     // ---- sx
        int bs = blk - 256;
        int b = bs >> 4;
        int c0 = (bs & 15) * 16;
        int r = t >> 5;             // 0..15
        int w32 = t & 31;
        const float* xr = x + ((size_t)b * NC + c0 + r) * NN;
        float s = 0.f;
#pragma unroll
        for (int k = 0; k < 24; ++k) {
            floatx4 v = *(const floatx4*)(xr + (size_t)(w32 + k * 32) * 4);
            s += v[0] + v[1] + v[2] + v[3];
        }
#pragma unroll
        for (int off = 16; off; off >>= 1) s += __shfl_down(s, off, 32);
        if (w32 == 0) sx[b * NC + c0 + r] = s;
        return;
    }

    // ---- G partial
    int b = blk >> 5;
    int n0 = (blk & 31) * 96;
    int lane = t & 63, wave = t >> 6;
    int lm = lane & 15, lh = lane >> 4, lk = lh * 8;
    int wr = wave >> 2;             // 0..1: row half (128)
    int wc = wave & 3;              // 0..3: col quarter (64)
    const float* xb = x + (size_t)b * NC * NN;

    // stage: 256 rows x 96 n, fp32 -> bf16 (issue all 12 loads, then write)
    floatx4 xv[12];
#pragma unroll
    for (int p = 0; p < 12; ++p) {
        int id = p * 512 + t;        // float4 id over 6144
        int row = id / 24;
        int c4 = (id % 24) * 4;
        xv[p] = *(const floatx4*)(xb + (size_t)row * NN + n0 + c4);
    }
#pragma unroll
    for (int p = 0; p < 12; ++p) {
        int id = p * 512 + t;
        int row = id / 24;
        int c4 = (id % 24) * 4;
        short4v o;
#pragma unroll
        for (int j = 0; j < 4; ++j) o[j] = f2s(xv[p][j]);
        *(short4v*)&Xs[row][c4] = o;
    }
    __syncthreads();

    floatx4 zero = {0.f, 0.f, 0.f, 0.f};
    floatx4 acc[8][4];
#pragma unroll
    for (int i = 0; i < 8; ++i)
#pragma unroll
        for (int j = 0; j < 4; ++j) acc[i][j] = zero;

#pragma unroll
    for (int kk = 0; kk < 96; kk += 32) {
        short8 af[8], bf[4];
#pragma unroll
        for (int i = 0; i < 8; ++i)
            af[i] = *(const short8*)&Xs[wr * 128 + i * 16 + lm][kk + lk];
#pragma unroll
        for (int j = 0; j < 4; ++j)
            bf[j] = *(const short8*)&Xs[wc * 64 + j * 16 + lm][kk + lk];
#pragma unroll
        for (int i = 0; i < 8; ++i)
#pragma unroll
            for (int j = 0; j < 4; ++j)
                acc[i][j] = __builtin_amdgcn_mfma_f32_16x16x32_bf16(
                    af[i], bf[j], acc[i][j], 0, 0, 0);
    }

    short* Gf = GpartS + (size_t)blk * 65536;
#pragma unroll
    for (int i = 0; i < 8; ++i)
#pragma unroll
        for (int j = 0; j < 4; ++j)
#pragma unroll
            for (int rr = 0; rr < 4; ++rr)
                Gf[(size_t)(wr * 128 + i * 16 + lh * 4 + rr) * NC
                   + wc * 64 + j * 16 + lm] = f2s(acc[i][j][rr]);
}

// ---------------------------------------------------------------------------
// gredUV: grid 521 x 256 thr.
//   blk 0..511   -> G[b][e] = sum_p GpartS (bf16 in, fp32 out; streaming)
//   blk 512..515 -> U = w_w . g_w   (K-halved LDS staging, 37 KB)
//   blk 516..519 -> VT[c'][k] = sum_e theta_w[e,c'] phi_w[e,k]
//   blk 520      -> q = phi_w^T theta_b ; u1 = w_w g_b ; vb = theta_w^T phi_b
// ---------------------------------------------------------------------------
__global__ __launch_bounds__(256)
void gredUV_kernel(const short* __restrict__ GpartS,
                   const float* __restrict__ g_w, const float* __restrict__ g_b,
                   const float* __restrict__ theta_w, const float* __restrict__ theta_b,
                   const float* __restrict__ phi_w, const float* __restrict__ phi_b,
                   const float* __restrict__ w_w,
                   float* __restrict__ G, float* __restrict__ U,
                   float* __restrict__ VT, float* __restrict__ qv,
                   float* __restrict__ u1v, float* __restrict__ vbv)
{
    __shared__ short TA[128][72];
    __shared__ short TB[128][72];
    int blk = blockIdx.x;
    int t = threadIdx.x;

    if (blk < 512) {          // ---- G reduce
        int idx = blk * 256 + t;            // float4-output id, 131072 total
        int b = idx >> 14;
        int fo = (idx & 16383) * 4;
        const short* src = GpartS + (size_t)b * 32 * 65536 + fo;
        floatx4 s = {0.f, 0.f, 0.f, 0.f};
#pragma unroll 8
        for (int p = 0; p < NCH; ++p) {
            short4v v = *(const short4v*)(src + (size_t)p * 65536);
            s[0] += s2f(v[0]); s[1] += s2f(v[1]);
            s[2] += s2f(v[2]); s[3] += s2f(v[3]);
        }
        *(floatx4*)(G + (size_t)b * 65536 + fo) = s;
        return;
    }
    if (blk == 520) {         // ---- small vectors
        int c = t;
        float s_q = 0.f, s_vb = 0.f, s_u1 = 0.f;
#pragma unroll
        for (int e = 0; e < 128; ++e) {
            s_q  += phi_w[(size_t)e * NC + c] * theta_b[e];
            s_vb += theta_w[(size_t)e * NC + c] * phi_b[e];
        }
        const float* wr_ = w_w + (size_t)c * ND;
#pragma unroll
        for (int d = 0; d < 32; ++d) {
            floatx4 v = *(const floatx4*)(wr_ + d * 4);
            floatx4 gb = *(const floatx4*)(g_b + d * 4);
            s_u1 += v[0]*gb[0] + v[1]*gb[1] + v[2]*gb[2] + v[3]*gb[3];
        }
        qv[c] = s_q; vbv[c] = s_vb; u1v[c] = s_u1;
        return;
    }

    int lane = t & 63, wave = t >> 6;
    int lm = lane & 15, lh = lane >> 4, lk = lh * 8;
    int wr = wave >> 1, wc = wave & 1;
    floatx4 zero = {0.f, 0.f, 0.f, 0.f};
    floatx4 acc[4][4];
#pragma unroll
    for (int i = 0; i < 4; ++i)
#pragma unroll
        for (int j = 0; j < 4; ++j) acc[i][j] = zero;

    if (blk < 516) {          // ---- U tile (K = d, halved)
        int ti = blk - 512, tr = ti >> 1, tc = ti & 1;
#pragma unroll
        for (int dh = 0; dh < 2; ++dh) {
            __syncthreads();
            // TB[cm][dl] = g_w[dh*64+dl][tc*128+cm]
#pragma unroll
            for (int p = 0; p < 8; ++p) {
                int id = p * 256 + t;        // float4 id over 2048
                int dl = id >> 5;            // 0..63
                int c4 = (id & 31) * 4;
                floatx4 v = *(const floatx4*)(g_w + (size_t)(dh * 64 + dl) * NC
                                              + tc * 128 + c4);
#pragma unroll
                for (int j = 0; j < 4; ++j) TB[c4 + j][dl] = f2s(v[j]);
            }
            __syncthreads();
#pragma unroll
            for (int kk = 0; kk < 64; kk += 32) {
                short8 af[4], bf[4];
#pragma unroll
                for (int i = 0; i < 4; ++i)
                    af[i] = ld8cvt(w_w + (size_t)(tr * 128 + wr * 64 + i * 16 + lm) * ND
                                   + dh * 64 + kk + lk);
#pragma unroll
                for (int j = 0; j < 4; ++j)
                    bf[j] = *(const short8*)&TB[wc * 64 + j * 16 + lm][kk + lk];
#pragma unroll
                for (int i = 0; i < 4; ++i)
#pragma unroll
                    for (int j = 0; j < 4; ++j)
                        acc[i][j] = __builtin_amdgcn_mfma_f32_16x16x32_bf16(
                            af[i], bf[j], acc[i][j], 0, 0, 0);
            }
        }
#pragma unroll
        for (int i = 0; i < 4; ++i)
#pragma unroll
            for (int j = 0; j < 4; ++j)
#pragma unroll
                for (int rr = 0; rr < 4; ++rr)
                    U[(size_t)(tr * 128 + wr * 64 + i * 16 + lh * 4 + rr) * NC
                      + tc * 128 + wc * 64 + j * 16 + lm] = acc[i][j][rr];
    } else {                  // ---- VT tile (K = e, halved)
        int ti = blk - 516, tr = ti >> 1, tc = ti & 1;
#pragma unroll
        for (int eh = 0; eh < 2; ++eh) {
            __syncthreads();
#pragma unroll
            for (int p = 0; p < 8; ++p) {
                int id = p * 256 + t;
                int el = id >> 5;            // 0..63
                int c4 = (id & 31) * 4;
                floatx4 a = *(const floatx4*)(theta_w + (size_t)(eh * 64 + el) * NC
                                              + tr * 128 + c4);
                floatx4 bb = *(const floatx4*)(phi_w + (size_t)(eh * 64 + el) * NC
                                               + tc * 128 + c4);
#pragma unroll
                for (int j = 0; j < 4; ++j) {
                    TA[c4 + j][el] = f2s(a[j]);
                    TB[c4 + j][el] = f2s(bb[j]);
                }
            }
            __syncthreads();
#pragma unroll
            for (int kk = 0; kk < 64; kk += 32) {
                short8 af[4], bf[4];
#pragma unroll
                for (int i = 0; i < 4; ++i)
                    af[i] = *(const short8*)&TA[wr * 64 + i * 16 + lm][kk + lk];
#pragma unroll
                for (int j = 0; j < 4; ++j)
                    bf[j] = *(const short8*)&TB[wc * 64 + j * 16 + lm][kk + lk];
#pragma unroll
                for (int i = 0; i < 4; ++i)
#pragma unroll
                    for (int j = 0; j < 4; ++j)
                        acc[i][j] = __builtin_amdgcn_mfma_f32_16x16x32_bf16(
                            af[i], bf[j], acc[i][j], 0, 0, 0);
            }
        }
#pragma unroll
        for (int i = 0; i < 4; ++i)
#pragma unroll
            for (int j = 0; j < 4; ++j)
#pragma unroll
                for (int rr = 0; rr < 4; ++rr)
                    VT[(size_t)(tr * 128 + wr * 64 + i * 16 + lh * 4 + rr) * NC
                       + tc * 128 + wc * 64 + j * 16 + lm] = acc[i][j][rr];
    }
}

// ---------------------------------------------------------------------------
// qf: blk 0..31 -> Qf tile via T = U.G (LDS bf16) then Qf = T.VT^T; u2/va
//     computed locally (cheap matvecs) -- no u2g/vag buffers.
//     blk 32..39 -> per-batch C2 (m = Gq, um = Um, u2 = U sx, rank-1 terms)
// ---------------------------------------------------------------------------
union QSm {
    short T[128][264];                        // 67.6 KB
    struct { float ql[256]; float sxl[256]; float ml[256]; } v;
};

__global__ __launch_bounds__(256)
void qf_kernel(const float* __restrict__ G, const float* __restrict__ U,
               const float* __restrict__ VT, const float* __restrict__ qv,
               const float* __restrict__ u1v, const float* __restrict__ vbv,
               const float* __restrict__ sx,
               const float* __restrict__ phi_b, const float* __restrict__ theta_b,
               const float* __restrict__ w_b,
               const float* __restrict__ gamma, const float* __restrict__ beta,
               const float* __restrict__ mean, const float* __restrict__ var,
               short* __restrict__ QfB, float* __restrict__ C2g)
{
    __shared__ QSm sm;
    __shared__ float sxq[256], val[128], u2l[128];
    int blk = blockIdx.x;
    int t = threadIdx.x;

    if (blk >= 32) {          // ---- C2 blocks
        int b = blk - 32;
        if (t < 64) {
            *(floatx4*)&sm.v.ql[t * 4]  = *(const floatx4*)(qv + t * 4);
            *(floatx4*)&sm.v.sxl[t * 4] = *(const floatx4*)(sx + b * NC + t * 4);
        }
        __syncthreads();
        float s1 = 0.f, s2 = 0.f;
#pragma unroll 8
        for (int k = 0; k < 256; ++k) s1 += sm.v.sxl[k] * sm.v.ql[k];
#pragma unroll 8
        for (int e = 0; e < 128; ++e) s2 += phi_b[e] * theta_b[e];
        {   // m = G q
            const float* Gr = G + (size_t)b * 65536 + (size_t)t * 256;
            float m = 0.f;
#pragma unroll
            for (int k = 0; k < 64; ++k) {
                floatx4 v = *(const floatx4*)(Gr + k * 4);
                m += v[0]*sm.v.ql[k*4] + v[1]*sm.v.ql[k*4+1]
                   + v[2]*sm.v.ql[k*4+2] + v[3]*sm.v.ql[k*4+3];
            }
            sm.v.ml[t] = m;
        }
        __syncthreads();
        float um = 0.f, u2 = 0.f;
        const float* Ur = U + (size_t)t * 256;
#pragma unroll
        for (int k = 0; k < 64; ++k) {
            floatx4 u = *(const floatx4*)(Ur + k * 4);
            um += u[0]*sm.v.ml[k*4] + u[1]*sm.v.ml[k*4+1]
                + u[2]*sm.v.ml[k*4+2] + u[3]*sm.v.ml[k*4+3];
            u2 += u[0]*sm.v.sxl[k*4] + u[1]*sm.v.sxl[k*4+1]
                + u[2]*sm.v.sxl[k*4+2] + u[3]*sm.v.sxl[k*4+3];
        }
        float u1c = u1v[t];
        float c2raw = (um + u1c * s1 + (u2 + (float)NN * u1c) * s2) * (1.f / (float)NN);
        float iv = gamma[t] * rsqrtf(var[t] + BN_EPS);
        C2g[b * NC + t] = iv * (c2raw + w_b[t] - mean[t]) + beta[t];
        return;
    }

    // ---- Qf tile blocks
    int b = blk >> 2;
    int tile = blk & 3, tr = tile >> 1, tc = tile & 1;
    int lane = t & 63, wave = t >> 6;
    int wr = wave >> 1, wc = wave & 1;
    int lm = lane & 15, lh = lane >> 4, lk = lh * 8;
    const float* Gb = G + (size_t)b * 65536;
    floatx4 zero = {0.f, 0.f, 0.f, 0.f};

    // local u2 (c-range) and va (cp-range) matvecs
    if (t < 64) *(floatx4*)&sxq[t * 4] = *(const floatx4*)(sx + b * NC + t * 4);
    __syncthreads();
    {
        const float* Rr = (t < 128) ? (VT + (size_t)(tc * 128 + t) * NC)
                                    : (U + (size_t)(tr * 128 + (t - 128)) * NC);
        float s = 0.f;
#pragma unroll
        for (int k = 0; k < 64; ++k) {
            floatx4 v = *(const floatx4*)(Rr + k * 4);
            s += v[0]*sxq[k*4] + v[1]*sxq[k*4+1] + v[2]*sxq[k*4+2] + v[3]*sxq[k*4+3];
        }
        if (t < 128) val[t] = s; else u2l[t - 128] = s;
    }

    // T = U[tr-half] . G  (two k-half passes)
#pragma unroll
    for (int h2 = 0; h2 < 2; ++h2) {
        floatx4 acc[4][4];
#pragma unroll
        for (int i = 0; i < 4; ++i)
#pragma unroll
            for (int j = 0; j < 4; ++j) acc[i][j] = zero;
#pragma unroll 4
        for (int kk = 0; kk < 256; kk += 32) {      // K = cp
            short8 af[4], bf[4];
#pragma unroll
            for (int i = 0; i < 4; ++i)
                af[i] = ld8cvt(U + (size_t)(tr * 128 + wr * 64 + i * 16 + lm) * NC + kk + lk);
#pragma unroll
            for (int j = 0; j < 4; ++j)
                bf[j] = ld8cvt(Gb + (size_t)(h2 * 128 + wc * 64 + j * 16 + lm) * NC + kk + lk);
#pragma unroll
            for (int i = 0; i < 4; ++i)
#pragma unroll
                for (int j = 0; j < 4; ++j)
                    acc[i][j] = __builtin_amdgcn_mfma_f32_16x16x32_bf16(
                        af[i], bf[j], acc[i][j], 0, 0, 0);
        }
#pragma unroll
        for (int i = 0; i < 4; ++i)
#pragma unroll
            for (int j = 0; j < 4; ++j)
#pragma unroll
                for (int rr = 0; rr < 4; ++rr)
                    sm.T[wr * 64 + i * 16 + lh * 4 + rr]
                        [h2 * 128 + wc * 64 + j * 16 + lm] = f2s(acc[i][j][rr]);
    }
    __syncthreads();

    // Qf = T . VT^T  (K = k = 256, A from LDS, B from global VT)
    floatx4 acc2[4][4];
#pragma unroll
    for (int i = 0; i < 4; ++i)
#pragma unroll
        for (int j = 0; j < 4; ++j) acc2[i][j] = zero;
#pragma unroll 4
    for (int kk = 0; kk < 256; kk += 32) {
        short8 af[4], bf[4];
#pragma unroll
        for (int i = 0; i < 4; ++i)
            af[i] = *(const short8*)&sm.T[wr * 64 + i * 16 + lm][kk + lk];
#pragma unroll
        for (int j = 0; j < 4; ++j)
            bf[j] = ld8cvt(VT + (size_t)(tc * 128 + wc * 64 + j * 16 + lm) * NC + kk + lk);
#pragma unroll
        for (int i = 0; i < 4; ++i)
#pragma unroll
            for (int j = 0; j < 4; ++j)
                acc2[i][j] = __builtin_amdgcn_mfma_f32_16x16x32_bf16(
                    af[i], bf[j], acc2[i][j], 0, 0, 0);
    }
#pragma unroll
    for (int i = 0; i < 4; ++i) {
#pragma unroll
        for (int rr = 0; rr < 4; ++rr) {
            int cl = wr * 64 + i * 16 + lh * 4 + rr;
            int c = tr * 128 + cl;
            float u1c = u1v[c];
            float u2c = u2l[cl];
            float scl = gamma[c] * rsqrtf(var[c] + BN_EPS) * (1.f / (float)NN);
#pragma unroll
            for (int j = 0; j < 4; ++j) {
                int cpl = wc * 64 + j * 16 + lm;
                int cp = tc * 128 + cpl;
                float v = acc2[i][j][rr] + u1c * val[cpl]
                        + (u2c + (float)NN * u1c) * vbv[cp];
                QfB[(size_t)b * 65536 + (size_t)c * NC + cp] = f2s(v * scl);
            }
        }
    }
}

// ---------------------------------------------------------------------------
// out: out[c,n] = sum_c' Qf[c,c'] x[c',n] + C2[c] + x[c,n]
// grid 256 x 512 thr = 8 waves (4c x 2n). A direct from QfB (L2/L3-hot);
// x via LDS transpose with T14 reg-prefetch.
// ---------------------------------------------------------------------------
__global__ __launch_bounds__(512, 2)
void out_kernel(const short* __restrict__ QfB, const float* __restrict__ C2g,
                const float* __restrict__ x, float* __restrict__ out)
{
    __shared__ short Xs[96][72];
    int blk = blockIdx.x;
    int b = blk >> 5;
    int n0 = (blk & 31) * 96;
    int t = threadIdx.x, lane = t & 63, wave = t >> 6;
    int lm = lane & 15, lh = lane >> 4, lk = lh * 8;
    int wr = wave >> 1, wc = wave & 1;
    const float* xb = x + (size_t)b * NC * NN;
    const short* Qb = QfB + (size_t)b * 65536;

    floatx4 zero = {0.f, 0.f, 0.f, 0.f};
    floatx4 acc[4][3];
#pragma unroll
    for (int i = 0; i < 4; ++i)
#pragma unroll
        for (int j = 0; j < 3; ++j) acc[i][j] = zero;

    int sn = t % 96, cgp = t / 96;   // valid for t < 384
    float xf[16];
    if (t < 384) {
#pragma unroll
        for (int j = 0; j < 16; ++j)
            xf[j] = xb[(size_t)(cgp * 16 + j) * NN + n0 + sn];
    }

#pragma unroll
    for (int kt = 0; kt < NC; kt += 64) {
        __syncthreads();
        short8 af2[2][4];
#pragma unroll
        for (int h = 0; h < 2; ++h)
#pragma unroll
            for (int i = 0; i < 4; ++i)
                af2[h][i] = *(const short8*)(Qb
                        + (size_t)(wr * 64 + i * 16 + lm) * 256 + kt + h * 32 + lk);
        if (t < 384) {
            short8 s0, s1;
#pragma unroll
            for (int j = 0; j < 8; ++j) {
                s0[j] = f2s(xf[j]);
                s1[j] = f2s(xf[8 + j]);
            }
            *(short8*)&Xs[sn][cgp * 16]     = s0;
            *(short8*)&Xs[sn][cgp * 16 + 8] = s1;
        }
        __syncthreads();
        if (t < 384 && kt < NC - 64) {
#pragma unroll
            for (int j = 0; j < 16; ++j)
                xf[j] = xb[(size_t)(kt + 64 + cgp * 16 + j) * NN + n0 + sn];
        }
#pragma unroll
        for (int h = 0; h < 2; ++h) {
            short8 bfr[3];
#pragma unroll
            for (int j = 0; j < 3; ++j)
                bfr[j] = *(const short8*)&Xs[wc * 48 + j * 16 + lm][h * 32 + lk];
#pragma unroll
            for (int i = 0; i < 4; ++i)
#pragma unroll
                for (int j = 0; j < 3; ++j)
                    acc[i][j] = __builtin_amdgcn_mfma_f32_16x16x32_bf16(
                        af2[h][i], bfr[j], acc[i][j], 0, 0, 0);
        }
    }

    float* Cf = out + (size_t)b * NC * NN;
#pragma unroll
    for (int i = 0; i < 4; ++i) {
#pragma unroll
        for (int rr = 0; rr < 4; ++rr) {
            int c = wr * 64 + i * 16 + lh * 4 + rr;
            float c2 = C2g[b * NC + c];
#pragma unroll
            for (int j = 0; j < 3; ++j) {
                size_t idx = (size_t)c * NN + n0 + wc * 48 + j * 16 + lm;
                Cf[idx] = acc[i][j][rr] + c2 + xb[idx];
            }
        }
    }
}

extern "C" void kernel_launch(void* const* d_in, const int* in_sizes, int n_in,
                              void* d_out, int out_size, void* d_ws, size_t ws_size,
                              hipStream_t stream)
{
    const float* x       = (const float*)d_in[0];
    const float* g_w     = (const float*)d_in[1];
    const float* g_b     = (const float*)d_in[2];
    const float* theta_w = (const float*)d_in[3];
    const float* theta_b = (const float*)d_in[4];
    const float* phi_w   = (const float*)d_in[5];
    const float* phi_b   = (const float*)d_in[6];
    const float* w_w     = (const float*)d_in[7];
    const float* w_b     = (const float*)d_in[8];
    const float* gamma   = (const float*)d_in[9];
    const float* beta    = (const float*)d_in[10];
    const float* mean    = (const float*)d_in[11];
    const float* var     = (const float*)d_in[12];
    (void)in_sizes; (void)n_in; (void)out_size; (void)ws_size;

    char* w = (char*)d_ws;
    float* sx    = (float*)w; w += (size_t)NB * NC * 4;               // 8 KB
    float* C2g   = (float*)w; w += (size_t)NB * NC * 4;               // 8 KB
    float* qv    = (float*)w; w += (size_t)NC * 4;                    // 1 KB
    float* u1v   = (float*)w; w += (size_t)NC * 4;                    // 1 KB
    float* vbv   = (float*)w; w += (size_t)NC * 4;                    // 1 KB
    w = (char*)(((size_t)w + 255) & ~(size_t)255);
    float* U     = (float*)w; w += (size_t)NC * NC * 4;               // 256 KB
    float* VT    = (float*)w; w += (size_t)NC * NC * 4;               // 256 KB
    float* G     = (float*)w; w += (size_t)NB * NC * NC * 4;          // 2 MB
    short* GpartS= (short*)w; w += (size_t)NB * NCH * NC * NC * 2;    // 32 MB
    short* QfB   = (short*)w; w += (size_t)NB * NC * NC * 2;          // 1 MB

    front_kernel<<<dim3(384), dim3(512), 0, stream>>>(x, GpartS, sx);

    gredUV_kernel<<<dim3(521), dim3(256), 0, stream>>>(
        GpartS, g_w, g_b, theta_w, theta_b, phi_w, phi_b, w_w,
        G, U, VT, qv, u1v, vbv);

    qf_kernel<<<dim3(40), dim3(256), 0, stream>>>(
        G, U, VT, qv, u1v, vbv, sx,
        phi_b, theta_b, w_b, gamma, beta, mean, var, QfB, C2g);

    out_kernel<<<dim3(256), dim3(512), 0, stream>>>(QfB, C2g, x, (float*)d_out);
}

// Round 8
// 169.253 us; speedup vs baseline: 1.3970x; 1.1054x over previous
//
#include <hip/hip_runtime.h>
#include <hip/hip_bf16.h>
#include <cstddef>

typedef __attribute__((ext_vector_type(8))) short short8;
typedef __attribute__((ext_vector_type(4))) short short4v;
typedef __attribute__((ext_vector_type(4))) float floatx4;
typedef __hip_bfloat16 bf16;

#define NB 8
#define NC 256
#define ND 128
#define NN 3072
#define NCH 32            /* n-chunks for G = x x^T (96 each) */
#define BN_EPS 1e-5f

static __device__ __forceinline__ short f2s(float v) {
    bf16 h = __float2bfloat16(v);
    return *reinterpret_cast<short*>(&h);
}
static __device__ __forceinline__ float s2f(short s) {
    unsigned int u = ((unsigned int)(unsigned short)s) << 16;
    return __uint_as_float(u);
}
// load 8 consecutive fp32, convert to bf16 short8 (MFMA operand)
static __device__ __forceinline__ short8 ld8cvt(const float* p) {
    floatx4 a = *(const floatx4*)p, b = *(const floatx4*)(p + 4);
    short8 r;
    r[0] = f2s(a[0]); r[1] = f2s(a[1]); r[2] = f2s(a[2]); r[3] = f2s(a[3]);
    r[4] = f2s(b[0]); r[5] = f2s(b[1]); r[6] = f2s(b[2]); r[7] = f2s(b[3]);
    return r;
}

// ---------------------------------------------------------------------------
// front: grid 384 x 512 thr.  (unchanged from R7 - passed)
//   blk 0..255  -> G-partial: stages x[256 c][96 n] -> LDS bf16 once,
//     computes full 256x256 partial X.X^T, stores Gpart bf16.
//   blk 256..383 -> sx[b][c] = sum_n x[b,c,n]
// ---------------------------------------------------------------------------
__global__ __launch_bounds__(512, 2)
void front_kernel(const float* __restrict__ x, short* __restrict__ GpartS,
                  float* __restrict__ sx)
{
    __shared__ short Xs[256][104];   // 53.2 KB
    int blk = blockIdx.x;
    int t = threadIdx.x;

    if (blk >= 256) {     // ---- sx
        int bs = blk - 256;
        int b = bs >> 4;
        int c0 = (bs & 15) * 16;
        int r = t >> 5;             // 0..15
        int w32 = t & 31;
        const float* xr = x + ((size_t)b * NC + c0 + r) * NN;
        float s = 0.f;
#pragma unroll
        for (int k = 0; k < 24; ++k) {
            floatx4 v = *(const floatx4*)(xr + (size_t)(w32 + k * 32) * 4);
            s += v[0] + v[1] + v[2] + v[3];
        }
#pragma unroll
        for (int off = 16; off; off >>= 1) s += __shfl_down(s, off, 32);
        if (w32 == 0) sx[b * NC + c0 + r] = s;
        return;
    }

    // ---- G partial
    int b = blk >> 5;
    int n0 = (blk & 31) * 96;
    int lane = t & 63, wave = t >> 6;
    int lm = lane & 15, lh = lane >> 4, lk = lh * 8;
    int wr = wave >> 2;             // 0..1: row half (128)
    int wc = wave & 3;              // 0..3: col quarter (64)
    const float* xb = x + (size_t)b * NC * NN;

    floatx4 xv[12];
#pragma unroll
    for (int p = 0; p < 12; ++p) {
        int id = p * 512 + t;        // float4 id over 6144
        int row = id / 24;
        int c4 = (id % 24) * 4;
        xv[p] = *(const floatx4*)(xb + (size_t)row * NN + n0 + c4);
    }
#pragma unroll
    for (int p = 0; p < 12; ++p) {
        int id = p * 512 + t;
        int row = id / 24;
        int c4 = (id % 24) * 4;
        short4v o;
#pragma unroll
        for (int j = 0; j < 4; ++j) o[j] = f2s(xv[p][j]);
        *(short4v*)&Xs[row][c4] = o;
    }
    __syncthreads();

    floatx4 zero = {0.f, 0.f, 0.f, 0.f};
    floatx4 acc[8][4];
#pragma unroll
    for (int i = 0; i < 8; ++i)
#pragma unroll
        for (int j = 0; j < 4; ++j) acc[i][j] = zero;

#pragma unroll
    for (int kk = 0; kk < 96; kk += 32) {
        short8 af[8], bf[4];
#pragma unroll
        for (int i = 0; i < 8; ++i)
            af[i] = *(const short8*)&Xs[wr * 128 + i * 16 + lm][kk + lk];
#pragma unroll
        for (int j = 0; j < 4; ++j)
            bf[j] = *(const short8*)&Xs[wc * 64 + j * 16 + lm][kk + lk];
#pragma unroll
        for (int i = 0; i < 8; ++i)
#pragma unroll
            for (int j = 0; j < 4; ++j)
                acc[i][j] = __builtin_amdgcn_mfma_f32_16x16x32_bf16(
                    af[i], bf[j], acc[i][j], 0, 0, 0);
    }

    short* Gf = GpartS + (size_t)blk * 65536;
#pragma unroll
    for (int i = 0; i < 8; ++i)
#pragma unroll
        for (int j = 0; j < 4; ++j)
#pragma unroll
            for (int rr = 0; rr < 4; ++rr)
                Gf[(size_t)(wr * 128 + i * 16 + lh * 4 + rr) * NC
                   + wc * 64 + j * 16 + lm] = f2s(acc[i][j][rr]);
}

// ---------------------------------------------------------------------------
// gredUV: grid 521 x 256 thr.
//   blk 0..511   -> G[b] = sum_p GpartS (fp32 out + bf16 copy Gb16)
//   blk 512..515 -> U = w_w . g_w   (fp32 + bf16 copy Ub16)
//   blk 516..519 -> VT = theta_w^T phi_w  (fp32 + bf16 copy VTb16)
//   blk 520      -> q, u1, vb vectors
// ---------------------------------------------------------------------------
__global__ __launch_bounds__(256)
void gredUV_kernel(const short* __restrict__ GpartS,
                   const float* __restrict__ g_w, const float* __restrict__ g_b,
                   const float* __restrict__ theta_w, const float* __restrict__ theta_b,
                   const float* __restrict__ phi_w, const float* __restrict__ phi_b,
                   const float* __restrict__ w_w,
                   float* __restrict__ G, short* __restrict__ Gb16,
                   float* __restrict__ U, short* __restrict__ Ub16,
                   float* __restrict__ VT, short* __restrict__ VTb16,
                   float* __restrict__ qv, float* __restrict__ u1v,
                   float* __restrict__ vbv)
{
    __shared__ short TA[128][72];
    __shared__ short TB[128][72];
    int blk = blockIdx.x;
    int t = threadIdx.x;

    if (blk < 512) {          // ---- G reduce
        int idx = blk * 256 + t;            // float4-output id, 131072 total
        int b = idx >> 14;
        int fo = (idx & 16383) * 4;
        const short* src = GpartS + (size_t)b * 32 * 65536 + fo;
        floatx4 s = {0.f, 0.f, 0.f, 0.f};
#pragma unroll 8
        for (int p = 0; p < NCH; ++p) {
            short4v v = *(const short4v*)(src + (size_t)p * 65536);
            s[0] += s2f(v[0]); s[1] += s2f(v[1]);
            s[2] += s2f(v[2]); s[3] += s2f(v[3]);
        }
        *(floatx4*)(G + (size_t)b * 65536 + fo) = s;
        short4v o;
#pragma unroll
        for (int j = 0; j < 4; ++j) o[j] = f2s(s[j]);
        *(short4v*)(Gb16 + (size_t)b * 65536 + fo) = o;
        return;
    }
    if (blk == 520) {         // ---- small vectors
        int c = t;
        float s_q = 0.f, s_vb = 0.f, s_u1 = 0.f;
#pragma unroll
        for (int e = 0; e < 128; ++e) {
            s_q  += phi_w[(size_t)e * NC + c] * theta_b[e];
            s_vb += theta_w[(size_t)e * NC + c] * phi_b[e];
        }
        const float* wr_ = w_w + (size_t)c * ND;
#pragma unroll
        for (int d = 0; d < 32; ++d) {
            floatx4 v = *(const floatx4*)(wr_ + d * 4);
            floatx4 gb = *(const floatx4*)(g_b + d * 4);
            s_u1 += v[0]*gb[0] + v[1]*gb[1] + v[2]*gb[2] + v[3]*gb[3];
        }
        qv[c] = s_q; vbv[c] = s_vb; u1v[c] = s_u1;
        return;
    }

    int lane = t & 63, wave = t >> 6;
    int lm = lane & 15, lh = lane >> 4, lk = lh * 8;
    int wr = wave >> 1, wc = wave & 1;
    floatx4 zero = {0.f, 0.f, 0.f, 0.f};
    floatx4 acc[4][4];
#pragma unroll
    for (int i = 0; i < 4; ++i)
#pragma unroll
        for (int j = 0; j < 4; ++j) acc[i][j] = zero;

    if (blk < 516) {          // ---- U tile (K = d, halved staging)
        int ti = blk - 512, tr = ti >> 1, tc = ti & 1;
#pragma unroll
        for (int dh = 0; dh < 2; ++dh) {
            __syncthreads();
#pragma unroll
            for (int p = 0; p < 8; ++p) {
                int id = p * 256 + t;        // float4 id over 2048
                int dl = id >> 5;            // 0..63
                int c4 = (id & 31) * 4;
                floatx4 v = *(const floatx4*)(g_w + (size_t)(dh * 64 + dl) * NC
                                              + tc * 128 + c4);
#pragma unroll
                for (int j = 0; j < 4; ++j) TB[c4 + j][dl] = f2s(v[j]);
            }
            __syncthreads();
#pragma unroll
            for (int kk = 0; kk < 64; kk += 32) {
                short8 af[4], bf[4];
#pragma unroll
                for (int i = 0; i < 4; ++i)
                    af[i] = ld8cvt(w_w + (size_t)(tr * 128 + wr * 64 + i * 16 + lm) * ND
                                   + dh * 64 + kk + lk);
#pragma unroll
                for (int j = 0; j < 4; ++j)
                    bf[j] = *(const short8*)&TB[wc * 64 + j * 16 + lm][kk + lk];
#pragma unroll
                for (int i = 0; i < 4; ++i)
#pragma unroll
                    for (int j = 0; j < 4; ++j)
                        acc[i][j] = __builtin_amdgcn_mfma_f32_16x16x32_bf16(
                            af[i], bf[j], acc[i][j], 0, 0, 0);
            }
        }
#pragma unroll
        for (int i = 0; i < 4; ++i)
#pragma unroll
            for (int j = 0; j < 4; ++j)
#pragma unroll
                for (int rr = 0; rr < 4; ++rr) {
                    size_t off = (size_t)(tr * 128 + wr * 64 + i * 16 + lh * 4 + rr) * NC
                               + tc * 128 + wc * 64 + j * 16 + lm;
                    float v = acc[i][j][rr];
                    U[off] = v; Ub16[off] = f2s(v);
                }
    } else {                  // ---- VT tile (K = e, halved staging)
        int ti = blk - 516, tr = ti >> 1, tc = ti & 1;
#pragma unroll
        for (int eh = 0; eh < 2; ++eh) {
            __syncthreads();
#pragma unroll
            for (int p = 0; p < 8; ++p) {
                int id = p * 256 + t;
                int el = id >> 5;            // 0..63
                int c4 = (id & 31) * 4;
                floatx4 a = *(const floatx4*)(theta_w + (size_t)(eh * 64 + el) * NC
                                              + tr * 128 + c4);
                floatx4 bb = *(const floatx4*)(phi_w + (size_t)(eh * 64 + el) * NC
                                               + tc * 128 + c4);
#pragma unroll
                for (int j = 0; j < 4; ++j) {
                    TA[c4 + j][el] = f2s(a[j]);
                    TB[c4 + j][el] = f2s(bb[j]);
                }
            }
            __syncthreads();
#pragma unroll
            for (int kk = 0; kk < 64; kk += 32) {
                short8 af[4], bf[4];
#pragma unroll
                for (int i = 0; i < 4; ++i)
                    af[i] = *(const short8*)&TA[wr * 64 + i * 16 + lm][kk + lk];
#pragma unroll
                for (int j = 0; j < 4; ++j)
                    bf[j] = *(const short8*)&TB[wc * 64 + j * 16 + lm][kk + lk];
#pragma unroll
                for (int i = 0; i < 4; ++i)
#pragma unroll
                    for (int j = 0; j < 4; ++j)
                        acc[i][j] = __builtin_amdgcn_mfma_f32_16x16x32_bf16(
                            af[i], bf[j], acc[i][j], 0, 0, 0);
            }
        }
#pragma unroll
        for (int i = 0; i < 4; ++i)
#pragma unroll
            for (int j = 0; j < 4; ++j)
#pragma unroll
                for (int rr = 0; rr < 4; ++rr) {
                    size_t off = (size_t)(tr * 128 + wr * 64 + i * 16 + lh * 4 + rr) * NC
                               + tc * 128 + wc * 64 + j * 16 + lm;
                    float v = acc[i][j][rr];
                    VT[off] = v; VTb16[off] = f2s(v);
                }
    }
}

// ---------------------------------------------------------------------------
// qf (R8): grid 72 x 512 thr.
//   blk 0..63 -> Qf tile 64c x 128cp (b = blk>>3, tr = (blk&7)>>1 row-64,
//     tc = blk&1 col-128). Stage 1: Ts = U[64 rows].G (K=256, bf16 global
//     operands, depth-1 reg prefetch, 8 waves = 32x64 each). Stage 2:
//     Qf = Ts.VT^T (A from LDS, B prefetched). Rank-1 + scale in epilogue.
//   blk 64..71 -> per-batch C2 (fp32 path, numerics unchanged).
// ---------------------------------------------------------------------------
__global__ __launch_bounds__(512, 2)
void qf_kernel(const float* __restrict__ G, const short* __restrict__ Gb16,
               const float* __restrict__ U, const short* __restrict__ Ub16,
               const float* __restrict__ VT, const short* __restrict__ VTb16,
               const float* __restrict__ qv, const float* __restrict__ u1v,
               const float* __restrict__ vbv, const float* __restrict__ sx,
               const float* __restrict__ phi_b, const float* __restrict__ theta_b,
               const float* __restrict__ w_b,
               const float* __restrict__ gamma, const float* __restrict__ beta,
               const float* __restrict__ mean, const float* __restrict__ var,
               short* __restrict__ QfB, float* __restrict__ C2g)
{
    __shared__ short Ts[64][264];          // 33.8 KB
    __shared__ float f0[256], f1[256], f2[256];
    int blk = blockIdx.x;
    int t = threadIdx.x;

    if (blk >= 64) {          // ---- C2 blocks (f0=q, f1=sx, f2=m)
        int b = blk - 64;
        if (t < 64) {
            *(floatx4*)&f0[t * 4] = *(const floatx4*)(qv + t * 4);
            *(floatx4*)&f1[t * 4] = *(const floatx4*)(sx + b * NC + t * 4);
        }
        __syncthreads();
        if (t < 256) {        // m = G q
            const float* Gr = G + (size_t)b * 65536 + (size_t)t * 256;
            float m = 0.f;
#pragma unroll
            for (int k = 0; k < 64; ++k) {
                floatx4 v = *(const floatx4*)(Gr + k * 4);
                m += v[0]*f0[k*4] + v[1]*f0[k*4+1] + v[2]*f0[k*4+2] + v[3]*f0[k*4+3];
            }
            f2[t] = m;
        }
        __syncthreads();
        if (t < 256) {
            float s1 = 0.f, s2 = 0.f;
#pragma unroll 8
            for (int k = 0; k < 256; ++k) s1 += f1[k] * f0[k];
#pragma unroll 8
            for (int e = 0; e < 128; ++e) s2 += phi_b[e] * theta_b[e];
            float um = 0.f, u2 = 0.f;
            const float* Ur = U + (size_t)t * 256;
#pragma unroll
            for (int k = 0; k < 64; ++k) {
                floatx4 u = *(const floatx4*)(Ur + k * 4);
                um += u[0]*f2[k*4] + u[1]*f2[k*4+1] + u[2]*f2[k*4+2] + u[3]*f2[k*4+3];
                u2 += u[0]*f1[k*4] + u[1]*f1[k*4+1] + u[2]*f1[k*4+2] + u[3]*f1[k*4+3];
            }
            float u1c = u1v[t];
            float c2raw = (um + u1c * s1 + (u2 + (float)NN * u1c) * s2) * (1.f / (float)NN);
            float iv = gamma[t] * rsqrtf(var[t] + BN_EPS);
            C2g[b * NC + t] = iv * (c2raw + w_b[t] - mean[t]) + beta[t];
        }
        return;
    }

    // ---- Qf tile blocks (f0=sx, f1=val[128], f2=u2l[64])
    int b = blk >> 3;
    int tile = blk & 7, tr = tile >> 1, tc = tile & 1;
    int lane = t & 63, wave = t >> 6;
    int lm = lane & 15, lh = lane >> 4, lk = lh * 8;
    const short* Gb = Gb16 + (size_t)b * 65536;
    floatx4 zero = {0.f, 0.f, 0.f, 0.f};

    if (t < 64) *(floatx4*)&f0[t * 4] = *(const floatx4*)(sx + b * NC + t * 4);
    __syncthreads();
    if (t < 128) {            // val[cp-local] = VT[tc*128+t] . sx
        const float* Rr = VT + (size_t)(tc * 128 + t) * NC;
        float s = 0.f;
#pragma unroll
        for (int k = 0; k < 64; ++k) {
            floatx4 v = *(const floatx4*)(Rr + k * 4);
            s += v[0]*f0[k*4] + v[1]*f0[k*4+1] + v[2]*f0[k*4+2] + v[3]*f0[k*4+3];
        }
        f1[t] = s;
    } else if (t < 192) {     // u2l[c-local] = U[tr*64+(t-128)] . sx
        const float* Rr = U + (size_t)(tr * 64 + (t - 128)) * NC;
        float s = 0.f;
#pragma unroll
        for (int k = 0; k < 64; ++k) {
            floatx4 v = *(const floatx4*)(Rr + k * 4);
            s += v[0]*f0[k*4] + v[1]*f0[k*4+1] + v[2]*f0[k*4+2] + v[3]*f0[k*4+3];
        }
        f2[t - 128] = s;
    }

    // ---- stage 1: Ts = U[tr*64 rows] . G  (64 x 256, K=256, prefetch d1)
    {
        int wvr = wave >> 2;      // 0..1: 32-row group
        int wvc = wave & 3;       // 0..3: 64-col group
        floatx4 acc[2][4];
#pragma unroll
        for (int i = 0; i < 2; ++i)
#pragma unroll
            for (int j = 0; j < 4; ++j) acc[i][j] = zero;

        short8 afc[2], bfc[4];
#pragma unroll
        for (int i = 0; i < 2; ++i)
            afc[i] = *(const short8*)(Ub16
                    + (size_t)(tr * 64 + wvr * 32 + i * 16 + lm) * NC + lk);
#pragma unroll
        for (int j = 0; j < 4; ++j)
            bfc[j] = *(const short8*)(Gb
                    + (size_t)(wvc * 64 + j * 16 + lm) * NC + lk);

#pragma unroll
        for (int kk = 0; kk < 256; kk += 32) {
            short8 afn[2], bfn[4];
            if (kk < 224) {
#pragma unroll
                for (int i = 0; i < 2; ++i)
                    afn[i] = *(const short8*)(Ub16
                            + (size_t)(tr * 64 + wvr * 32 + i * 16 + lm) * NC + kk + 32 + lk);
#pragma unroll
                for (int j = 0; j < 4; ++j)
                    bfn[j] = *(const short8*)(Gb
                            + (size_t)(wvc * 64 + j * 16 + lm) * NC + kk + 32 + lk);
            }
#pragma unroll
            for (int i = 0; i < 2; ++i)
#pragma unroll
                for (int j = 0; j < 4; ++j)
                    acc[i][j] = __builtin_amdgcn_mfma_f32_16x16x32_bf16(
                        afc[i], bfc[j], acc[i][j], 0, 0, 0);
            if (kk < 224) {
#pragma unroll
                for (int i = 0; i < 2; ++i) afc[i] = afn[i];
#pragma unroll
                for (int j = 0; j < 4; ++j) bfc[j] = bfn[j];
            }
        }
#pragma unroll
        for (int i = 0; i < 2; ++i)
#pragma unroll
            for (int j = 0; j < 4; ++j)
#pragma unroll
                for (int rr = 0; rr < 4; ++rr)
                    Ts[wvr * 32 + i * 16 + lh * 4 + rr]
                      [wvc * 64 + j * 16 + lm] = f2s(acc[i][j][rr]);
    }
    __syncthreads();

    // ---- stage 2: Qf = Ts . VT^T  (64 x 128, K=256, A from LDS, prefetch)
    {
        int qr = wave >> 1;       // 0..3: 16-row group
        int qc = wave & 1;        // 0..1: 64-col group
        floatx4 acc2[4];
#pragma unroll
        for (int j = 0; j < 4; ++j) acc2[j] = zero;

        short8 ac2, bc2[4];
        ac2 = *(const short8*)&Ts[qr * 16 + lm][lk];
#pragma unroll
        for (int j = 0; j < 4; ++j)
            bc2[j] = *(const short8*)(VTb16
                    + (size_t)(tc * 128 + qc * 64 + j * 16 + lm) * NC + lk);

#pragma unroll
        for (int kk = 0; kk < 256; kk += 32) {
            short8 an2, bn2[4];
            if (kk < 224) {
                an2 = *(const short8*)&Ts[qr * 16 + lm][kk + 32 + lk];
#pragma unroll
                for (int j = 0; j < 4; ++j)
                    bn2[j] = *(const short8*)(VTb16
                            + (size_t)(tc * 128 + qc * 64 + j * 16 + lm) * NC + kk + 32 + lk);
            }
#pragma unroll
            for (int j = 0; j < 4; ++j)
                acc2[j] = __builtin_amdgcn_mfma_f32_16x16x32_bf16(
                    ac2, bc2[j], acc2[j], 0, 0, 0);
            if (kk < 224) {
                ac2 = an2;
#pragma unroll
                for (int j = 0; j < 4; ++j) bc2[j] = bn2[j];
            }
        }

#pragma unroll
        for (int rr = 0; rr < 4; ++rr) {
            int cl = qr * 16 + lh * 4 + rr;          // 0..63
            int c = tr * 64 + cl;
            float u1c = u1v[c];
            float u2c = f2[cl];
            float scl = gamma[c] * rsqrtf(var[c] + BN_EPS) * (1.f / (float)NN);
#pragma unroll
            for (int j = 0; j < 4; ++j) {
                int cpl = qc * 64 + j * 16 + lm;     // 0..127
                int cp = tc * 128 + cpl;
                float v = acc2[j][rr] + u1c * f1[cpl]
                        + (u2c + (float)NN * u1c) * vbv[cp];
                QfB[(size_t)b * 65536 + (size_t)c * NC + cp] = f2s(v * scl);
            }
        }
    }
}

// ---------------------------------------------------------------------------
// out: out[c,n] = sum_c' Qf[c,c'] x[c',n] + C2[c] + x[c,n]   (unchanged)
// ---------------------------------------------------------------------------
__global__ __launch_bounds__(512, 2)
void out_kernel(const short* __restrict__ QfB, const float* __restrict__ C2g,
                const float* __restrict__ x, float* __restrict__ out)
{
    __shared__ short Xs[96][72];
    int blk = blockIdx.x;
    int b = blk >> 5;
    int n0 = (blk & 31) * 96;
    int t = threadIdx.x, lane = t & 63, wave = t >> 6;
    int lm = lane & 15, lh = lane >> 4, lk = lh * 8;
    int wr = wave >> 1, wc = wave & 1;
    const float* xb = x + (size_t)b * NC * NN;
    const short* Qb = QfB + (size_t)b * 65536;

    floatx4 zero = {0.f, 0.f, 0.f, 0.f};
    floatx4 acc[4][3];
#pragma unroll
    for (int i = 0; i < 4; ++i)
#pragma unroll
        for (int j = 0; j < 3; ++j) acc[i][j] = zero;

    int sn = t % 96, cgp = t / 96;   // valid for t < 384
    float xf[16];
    if (t < 384) {
#pragma unroll
        for (int j = 0; j < 16; ++j)
            xf[j] = xb[(size_t)(cgp * 16 + j) * NN + n0 + sn];
    }

#pragma unroll
    for (int kt = 0; kt < NC; kt += 64) {
        __syncthreads();
        short8 af2[2][4];
#pragma unroll
        for (int h = 0; h < 2; ++h)
#pragma unroll
            for (int i = 0; i < 4; ++i)
                af2[h][i] = *(const short8*)(Qb
                        + (size_t)(wr * 64 + i * 16 + lm) * 256 + kt + h * 32 + lk);
        if (t < 384) {
            short8 s0, s1;
#pragma unroll
            for (int j = 0; j < 8; ++j) {
                s0[j] = f2s(xf[j]);
                s1[j] = f2s(xf[8 + j]);
            }
            *(short8*)&Xs[sn][cgp * 16]     = s0;
            *(short8*)&Xs[sn][cgp * 16 + 8] = s1;
        }
        __syncthreads();
        if (t < 384 && kt < NC - 64) {
#pragma unroll
            for (int j = 0; j < 16; ++j)
                xf[j] = xb[(size_t)(kt + 64 + cgp * 16 + j) * NN + n0 + sn];
        }
#pragma unroll
        for (int h = 0; h < 2; ++h) {
            short8 bfr[3];
#pragma unroll
            for (int j = 0; j < 3; ++j)
                bfr[j] = *(const short8*)&Xs[wc * 48 + j * 16 + lm][h * 32 + lk];
#pragma unroll
            for (int i = 0; i < 4; ++i)
#pragma unroll
                for (int j = 0; j < 3; ++j)
                    acc[i][j] = __builtin_amdgcn_mfma_f32_16x16x32_bf16(
                        af2[h][i], bfr[j], acc[i][j], 0, 0, 0);
        }
    }

    float* Cf = out + (size_t)b * NC * NN;
#pragma unroll
    for (int i = 0; i < 4; ++i) {
#pragma unroll
        for (int rr = 0; rr < 4; ++rr) {
            int c = wr * 64 + i * 16 + lh * 4 + rr;
            float c2 = C2g[b * NC + c];
#pragma unroll
            for (int j = 0; j < 3; ++j) {
                size_t idx = (size_t)c * NN + n0 + wc * 48 + j * 16 + lm;
                Cf[idx] = acc[i][j][rr] + c2 + xb[idx];
            }
        }
    }
}

extern "C" void kernel_launch(void* const* d_in, const int* in_sizes, int n_in,
                              void* d_out, int out_size, void* d_ws, size_t ws_size,
                              hipStream_t stream)
{
    const float* x       = (const float*)d_in[0];
    const float* g_w     = (const float*)d_in[1];
    const float* g_b     = (const float*)d_in[2];
    const float* theta_w = (const float*)d_in[3];
    const float* theta_b = (const float*)d_in[4];
    const float* phi_w   = (const float*)d_in[5];
    const float* phi_b   = (const float*)d_in[6];
    const float* w_w     = (const float*)d_in[7];
    const float* w_b     = (const float*)d_in[8];
    const float* gamma   = (const float*)d_in[9];
    const float* beta    = (const float*)d_in[10];
    const float* mean    = (const float*)d_in[11];
    const float* var     = (const float*)d_in[12];
    (void)in_sizes; (void)n_in; (void)out_size; (void)ws_size;

    char* w = (char*)d_ws;
    float* sx    = (float*)w; w += (size_t)NB * NC * 4;               // 8 KB
    float* C2g   = (float*)w; w += (size_t)NB * NC * 4;               // 8 KB
    float* qv    = (float*)w; w += (size_t)NC * 4;                    // 1 KB
    float* u1v   = (float*)w; w += (size_t)NC * 4;                    // 1 KB
    float* vbv   = (float*)w; w += (size_t)NC * 4;                    // 1 KB
    w = (char*)(((size_t)w + 255) & ~(size_t)255);
    float* U     = (float*)w; w += (size_t)NC * NC * 4;               // 256 KB
    float* VT    = (float*)w; w += (size_t)NC * NC * 4;               // 256 KB
    short* Ub16  = (short*)w; w += (size_t)NC * NC * 2;               // 128 KB
    short* VTb16 = (short*)w; w += (size_t)NC * NC * 2;               // 128 KB
    float* G     = (float*)w; w += (size_t)NB * NC * NC * 4;          // 2 MB
    short* Gb16  = (short*)w; w += (size_t)NB * NC * NC * 2;          // 1 MB
    short* GpartS= (short*)w; w += (size_t)NB * NCH * NC * NC * 2;    // 32 MB
    short* QfB   = (short*)w; w += (size_t)NB * NC * NC * 2;          // 1 MB

    front_kernel<<<dim3(384), dim3(512), 0, stream>>>(x, GpartS, sx);

    gredUV_kernel<<<dim3(521), dim3(256), 0, stream>>>(
        GpartS, g_w, g_b, theta_w, theta_b, phi_w, phi_b, w_w,
        G, Gb16, U, Ub16, VT, VTb16, qv, u1v, vbv);

    qf_kernel<<<dim3(72), dim3(512), 0, stream>>>(
        G, Gb16, U, Ub16, VT, VTb16, qv, u1v, vbv, sx,
        phi_b, theta_b, w_b, gamma, beta, mean, var, QfB, C2g);

    out_kernel<<<dim3(256), dim3(512), 0, stream>>>(QfB, C2g, x, (float*)d_out);
}